// Round 1
// baseline (714.993 us; speedup 1.0000x reference)
//
#include <hip/hip_runtime.h>
#include <math.h>

#define N_NODES  200000
#define N_EDGES  1250000
#define D        64
#define NGRAPH   128
#define ZSTR     68   // padded LDS row stride (floats), 16B-aligned rows, breaks bank stride

// ---------------- edge scatter-add: A[dst] += H[src] ----------------
__global__ __launch_bounds__(256) void k_scatter(const float* __restrict__ H,
                                                 const int* __restrict__ srcs,
                                                 const int* __restrict__ dsts,
                                                 float* __restrict__ A) {
    long gt = (long)blockIdx.x * blockDim.x + threadIdx.x;
    int e = (int)(gt >> 6);
    int lane = (int)(gt & 63);
    if (e >= N_EDGES) return;
    int s = srcs[e];
    int d = dsts[e];
    atomicAdd(&A[(long)d * D + lane], H[(long)s * D + lane]);
}

// ---------------- per-node GIN MLP: Out = [relu](relu((X+A)@w1+b1)@w2+b2) ----
template<int FINAL_RELU>
__global__ __launch_bounds__(256, 2) void k_gin_mlp(
    const float* __restrict__ Xin, const float* __restrict__ Agg,
    const float* __restrict__ w1g, const float* __restrict__ b1g,
    const float* __restrict__ w2g, const float* __restrict__ b2g,
    float* __restrict__ Out)
{
    __shared__ float sw1[D][D];      // [k][c]
    __shared__ float sw2[D][D];      // [k][c]
    __shared__ float sz[D][ZSTR];    // [n][k]
    __shared__ float sy[D][ZSTR];    // [n][k]
    __shared__ float sb1[D], sb2[D];
    const int tid = threadIdx.x;
    const long nbase = (long)blockIdx.x * 64;

    // stage weights (4096 f32 each)
    #pragma unroll
    for (int i = 0; i < 4; ++i) {
        int f = tid + i * 256;
        ((float4*)sw1)[f] = ((const float4*)w1g)[f];
        ((float4*)sw2)[f] = ((const float4*)w2g)[f];
    }
    if (tid < D) { sb1[tid] = b1g[tid]; sb2[tid] = b2g[tid]; }

    // stage z = x + agg, row-major [n][k]
    #pragma unroll
    for (int i = 0; i < 4; ++i) {
        int f = tid + i * 256;       // float4 unit 0..1023
        int n = f >> 4;              // 0..63
        int kq = f & 15;             // 0..15
        long g = (nbase + n) * D + kq * 4;
        float4 xv = *(const float4*)(Xin + g);
        float4 av = *(const float4*)(Agg + g);
        float4 zv = make_float4(xv.x + av.x, xv.y + av.y, xv.z + av.z, xv.w + av.w);
        *(float4*)&sz[n][kq * 4] = zv;
    }
    __syncthreads();

    const int cg = tid & 15;   // cols  cg*4 .. cg*4+3
    const int ng = tid >> 4;   // nodes ng*4 .. ng*4+3
    float acc[4][4];

    // ---- layer 1 ----
    #pragma unroll
    for (int ni = 0; ni < 4; ++ni)
        #pragma unroll
        for (int ci = 0; ci < 4; ++ci) acc[ni][ci] = sb1[cg * 4 + ci];

    #pragma unroll 4
    for (int k = 0; k < D; ++k) {
        float4 wv = *(const float4*)&sw1[k][cg * 4];
        #pragma unroll
        for (int ni = 0; ni < 4; ++ni) {
            float zv = sz[ng * 4 + ni][k];
            acc[ni][0] += zv * wv.x;
            acc[ni][1] += zv * wv.y;
            acc[ni][2] += zv * wv.z;
            acc[ni][3] += zv * wv.w;
        }
    }
    #pragma unroll
    for (int ni = 0; ni < 4; ++ni)
        #pragma unroll
        for (int ci = 0; ci < 4; ++ci) {
            float v = acc[ni][ci];
            sy[ng * 4 + ni][cg * 4 + ci] = v > 0.f ? v : 0.f;
        }
    __syncthreads();

    // ---- layer 2 ----
    #pragma unroll
    for (int ni = 0; ni < 4; ++ni)
        #pragma unroll
        for (int ci = 0; ci < 4; ++ci) acc[ni][ci] = sb2[cg * 4 + ci];

    #pragma unroll 4
    for (int k = 0; k < D; ++k) {
        float4 wv = *(const float4*)&sw2[k][cg * 4];
        #pragma unroll
        for (int ni = 0; ni < 4; ++ni) {
            float yv = sy[ng * 4 + ni][k];
            acc[ni][0] += yv * wv.x;
            acc[ni][1] += yv * wv.y;
            acc[ni][2] += yv * wv.z;
            acc[ni][3] += yv * wv.w;
        }
    }
    #pragma unroll
    for (int ni = 0; ni < 4; ++ni) {
        float4 o;
        o.x = acc[ni][0]; o.y = acc[ni][1]; o.z = acc[ni][2]; o.w = acc[ni][3];
        if (FINAL_RELU) {
            o.x = o.x > 0.f ? o.x : 0.f;
            o.y = o.y > 0.f ? o.y : 0.f;
            o.z = o.z > 0.f ? o.z : 0.f;
            o.w = o.w > 0.f ? o.w : 0.f;
        }
        *(float4*)(Out + (nbase + ng * 4 + ni) * D + cg * 4) = o;
    }
}

// ---------------- pooling init ----------------
__global__ __launch_bounds__(256) void k_init_pool(float* __restrict__ psum,
                                                   float* __restrict__ pmax) {
    int t = blockIdx.x * blockDim.x + threadIdx.x;
    if (t < NGRAPH * D) {
        psum[t] = 0.f;
        pmax[t] = -INFINITY;
    }
}

__device__ inline void atomicMaxFloat(float* addr, float val) {
    if (val >= 0.f) atomicMax((int*)addr, __float_as_int(val));
    else            atomicMin((unsigned int*)addr, __float_as_uint(val));
}

// ---------------- pooling: segment sum + max over sorted batch ----------------
// one wave handles 16 consecutive nodes, flushing atomics on graph change
__global__ __launch_bounds__(256) void k_pool(const float* __restrict__ H,
                                              const int* __restrict__ batch,
                                              float* __restrict__ psum,
                                              float* __restrict__ pmax) {
    long gt = (long)blockIdx.x * blockDim.x + threadIdx.x;
    int wave = (int)(gt >> 6);
    int lane = (int)(gt & 63);
    int n0 = wave * 16;
    if (n0 >= N_NODES) return;
    int curg = batch[n0];
    float accs = 0.f;
    float accm = -INFINITY;
    #pragma unroll 4
    for (int i = 0; i < 16; ++i) {
        int n = n0 + i;
        if (n >= N_NODES) break;
        int g = batch[n];
        if (g != curg) {
            atomicAdd(&psum[curg * D + lane], accs);
            atomicMaxFloat(&pmax[curg * D + lane], accm);
            accs = 0.f; accm = -INFINITY; curg = g;
        }
        float v = H[(long)n * D + lane];
        accs += v;
        accm = accm > v ? accm : v;
    }
    atomicAdd(&psum[curg * D + lane], accs);
    atomicMaxFloat(&pmax[curg * D + lane], accm);
}

// ---------------- MLP head ----------------
__device__ inline float silu(float x) { return x / (1.f + expf(-x)); }

__global__ __launch_bounds__(128) void k_head(
    const float* __restrict__ psum, const float* __restrict__ pmax,
    const float* __restrict__ w0, const float* __restrict__ b0,
    const float* __restrict__ w1, const float* __restrict__ b1,
    const float* __restrict__ w2, const float* __restrict__ b2,
    const float* __restrict__ w3, const float* __restrict__ b3,
    const float* __restrict__ w4, const float* __restrict__ b4,
    float* __restrict__ out)
{
    __shared__ float bufA[128];
    __shared__ float bufB[128];
    int g = blockIdx.x, t = threadIdx.x;
    bufA[t] = (t < 64) ? psum[g * 64 + t] : pmax[g * 64 + (t - 64)];
    __syncthreads();
    // L0: 128 -> 128
    {
        float a = b0[t];
        for (int k = 0; k < 128; ++k) a += bufA[k] * w0[k * 128 + t];
        bufB[t] = silu(a);
    }
    __syncthreads();
    // L1: 128 -> 64
    if (t < 64) {
        float a = b1[t];
        for (int k = 0; k < 128; ++k) a += bufB[k] * w1[k * 64 + t];
        bufA[t] = silu(a);
    }
    __syncthreads();
    // L2: 64 -> 32
    if (t < 32) {
        float a = b2[t];
        for (int k = 0; k < 64; ++k) a += bufA[k] * w2[k * 32 + t];
        bufB[t] = silu(a);
    }
    __syncthreads();
    // L3: 32 -> 16
    if (t < 16) {
        float a = b3[t];
        for (int k = 0; k < 32; ++k) a += bufB[k] * w3[k * 16 + t];
        bufA[t] = silu(a);
    }
    __syncthreads();
    // L4: 16 -> 1
    if (t == 0) {
        float a = b4[0];
        for (int k = 0; k < 16; ++k) a += bufA[k] * w4[k];
        out[g] = a;
    }
}

extern "C" void kernel_launch(void* const* d_in, const int* in_sizes, int n_in,
                              void* d_out, int out_size, void* d_ws, size_t ws_size,
                              hipStream_t stream) {
    const float* x     = (const float*)d_in[0];
    const int*   ei    = (const int*)d_in[1];
    const int*   batch = (const int*)d_in[2];
    const float* c1w1 = (const float*)d_in[3];
    const float* c1b1 = (const float*)d_in[4];
    const float* c1w2 = (const float*)d_in[5];
    const float* c1b2 = (const float*)d_in[6];
    const float* c2w1 = (const float*)d_in[7];
    const float* c2b1 = (const float*)d_in[8];
    const float* c2w2 = (const float*)d_in[9];
    const float* c2b2 = (const float*)d_in[10];
    const float* hw0 = (const float*)d_in[11];
    const float* hb0 = (const float*)d_in[12];
    const float* hw1 = (const float*)d_in[13];
    const float* hb1 = (const float*)d_in[14];
    const float* hw2 = (const float*)d_in[15];
    const float* hb2 = (const float*)d_in[16];
    const float* hw3 = (const float*)d_in[17];
    const float* hb3 = (const float*)d_in[18];
    const float* hw4 = (const float*)d_in[19];
    const float* hb4 = (const float*)d_in[20];

    float* A    = (float*)d_ws;                      // 51.2 MB aggregation buffer
    float* H    = A + (size_t)N_NODES * D;           // 51.2 MB hidden buffer
    float* psum = H + (size_t)N_NODES * D;
    float* pmax = psum + NGRAPH * D;
    float* out  = (float*)d_out;

    const int* srcs = ei;
    const int* dsts = ei + N_EDGES;

    const int scatterBlocks = (int)(((long)N_EDGES * 64) / 256);  // 312500
    const int mlpBlocks = N_NODES / 64;                           // 3125
    const int poolBlocks = N_NODES / 64;                          // 3125 (16 nodes/wave)

    // conv1
    hipMemsetAsync(A, 0, (size_t)N_NODES * D * sizeof(float), stream);
    k_scatter<<<scatterBlocks, 256, 0, stream>>>(x, srcs, dsts, A);
    k_gin_mlp<1><<<mlpBlocks, 256, 0, stream>>>(x, A, c1w1, c1b1, c1w2, c1b2, H);

    // conv2 (writes H in place; per-block row ownership makes this safe)
    hipMemsetAsync(A, 0, (size_t)N_NODES * D * sizeof(float), stream);
    k_scatter<<<scatterBlocks, 256, 0, stream>>>(H, srcs, dsts, A);
    k_gin_mlp<0><<<mlpBlocks, 256, 0, stream>>>(H, A, c2w1, c2b1, c2w2, c2b2, H);

    // pooling
    k_init_pool<<<(NGRAPH * D + 255) / 256, 256, 0, stream>>>(psum, pmax);
    k_pool<<<poolBlocks, 256, 0, stream>>>(H, batch, psum, pmax);

    // head
    k_head<<<NGRAPH, 128, 0, stream>>>(psum, pmax,
                                       hw0, hb0, hw1, hb1, hw2, hb2, hw3, hb3, hw4, hb4,
                                       out);
}

// Round 2
// 480.666 us; speedup vs baseline: 1.4875x; 1.4875x over previous
//
#include <hip/hip_runtime.h>
#include <math.h>

#define N_NODES  200000
#define N_EDGES  1250000
#define D        64
#define NGRAPH   128
#define ZSTR     68   // padded LDS row stride (floats)

// ================= CSR build =================
// deg/rowptr array doubles: histogram writes counts into rowptr[], scans turn it
// into an exclusive prefix (row pointers), cursor[] is a working copy for fill.

__global__ __launch_bounds__(256) void k_hist(const int* __restrict__ dsts,
                                              int* __restrict__ deg) {
    int e = blockIdx.x * 256 + threadIdx.x;
    if (e < N_EDGES) atomicAdd(&deg[dsts[e]], 1);
}

// block scan over 1024 elements (256 threads x 4), in-place partials + block sums
__global__ __launch_bounds__(256) void k_scan1(int* __restrict__ data,
                                               int* __restrict__ blksum, int n) {
    __shared__ int s[256];
    int tid = threadIdx.x;
    int base = blockIdx.x * 1024 + tid * 4;
    int v0 = (base + 0 < n) ? data[base + 0] : 0;
    int v1 = (base + 1 < n) ? data[base + 1] : 0;
    int v2 = (base + 2 < n) ? data[base + 2] : 0;
    int v3 = (base + 3 < n) ? data[base + 3] : 0;
    int tsum = v0 + v1 + v2 + v3;
    s[tid] = tsum;
    __syncthreads();
    for (int off = 1; off < 256; off <<= 1) {
        int t = (tid >= off) ? s[tid - off] : 0;
        __syncthreads();
        s[tid] += t;
        __syncthreads();
    }
    int ex = s[tid] - tsum;   // exclusive prefix of this thread's chunk
    if (base + 0 < n) data[base + 0] = ex;            ex += v0;
    if (base + 1 < n) data[base + 1] = ex;            ex += v1;
    if (base + 2 < n) data[base + 2] = ex;            ex += v2;
    if (base + 3 < n) data[base + 3] = ex;
    if (tid == 255) blksum[blockIdx.x] = s[255];
}

__global__ __launch_bounds__(256) void k_scan2(int* __restrict__ blksum, int nblk) {
    __shared__ int s[256];
    int tid = threadIdx.x;
    int v = (tid < nblk) ? blksum[tid] : 0;
    s[tid] = v;
    __syncthreads();
    for (int off = 1; off < 256; off <<= 1) {
        int t = (tid >= off) ? s[tid - off] : 0;
        __syncthreads();
        s[tid] += t;
        __syncthreads();
    }
    if (tid < nblk) blksum[tid] = s[tid] - v;   // exclusive
}

__global__ __launch_bounds__(256) void k_scan3(int* __restrict__ rowptr,
                                               const int* __restrict__ blksum,
                                               int* __restrict__ cursor, int n) {
    int base = blockIdx.x * 1024 + threadIdx.x * 4;
    int off = blksum[blockIdx.x];
    #pragma unroll
    for (int j = 0; j < 4; ++j) {
        int i = base + j;
        if (i < n) {
            int r = rowptr[i] + off;
            rowptr[i] = r;
            cursor[i] = r;
        }
    }
    if (blockIdx.x == 0 && threadIdx.x == 0) rowptr[n] = N_EDGES;
}

__global__ __launch_bounds__(256) void k_fill(const int* __restrict__ srcs,
                                              const int* __restrict__ dsts,
                                              int* __restrict__ cursor,
                                              int* __restrict__ csr) {
    int e = blockIdx.x * 256 + threadIdx.x;
    if (e < N_EDGES) {
        int d = dsts[e];
        int pos = atomicAdd(&cursor[d], 1);
        csr[pos] = srcs[e];
    }
}

// ================= aggregation: A[n] = sum_{e: dst=n} H[src_e] =================
// one wave per node, lane = feature; 2-edge unroll for load ILP
__global__ __launch_bounds__(256) void k_agg(const float* __restrict__ H,
                                             const int* __restrict__ rowptr,
                                             const int* __restrict__ csr,
                                             float* __restrict__ A) {
    long gt = (long)blockIdx.x * 256 + threadIdx.x;
    int node = (int)(gt >> 6);
    int lane = (int)(gt & 63);
    if (node >= N_NODES) return;
    int i = rowptr[node];
    int end = rowptr[node + 1];
    float acc = 0.f;
    for (; i + 1 < end; i += 2) {
        int sa = csr[i];
        int sb = csr[i + 1];
        float va = H[(long)sa * D + lane];
        float vb = H[(long)sb * D + lane];
        acc += va;
        acc += vb;
    }
    if (i < end) acc += H[(long)csr[i] * D + lane];
    A[(long)node * D + lane] = acc;
}

// ================= per-node GIN MLP =================
template<int FINAL_RELU>
__global__ __launch_bounds__(256, 2) void k_gin_mlp(
    const float* __restrict__ Xin, const float* __restrict__ Agg,
    const float* __restrict__ w1g, const float* __restrict__ b1g,
    const float* __restrict__ w2g, const float* __restrict__ b2g,
    float* __restrict__ Out)
{
    __shared__ float sw1[D][D];
    __shared__ float sw2[D][D];
    __shared__ float sz[D][ZSTR];
    __shared__ float sy[D][ZSTR];
    __shared__ float sb1[D], sb2[D];
    const int tid = threadIdx.x;
    const long nbase = (long)blockIdx.x * 64;

    #pragma unroll
    for (int i = 0; i < 4; ++i) {
        int f = tid + i * 256;
        ((float4*)sw1)[f] = ((const float4*)w1g)[f];
        ((float4*)sw2)[f] = ((const float4*)w2g)[f];
    }
    if (tid < D) { sb1[tid] = b1g[tid]; sb2[tid] = b2g[tid]; }

    #pragma unroll
    for (int i = 0; i < 4; ++i) {
        int f = tid + i * 256;
        int n = f >> 4;
        int kq = f & 15;
        long g = (nbase + n) * D + kq * 4;
        float4 xv = *(const float4*)(Xin + g);
        float4 av = *(const float4*)(Agg + g);
        float4 zv = make_float4(xv.x + av.x, xv.y + av.y, xv.z + av.z, xv.w + av.w);
        *(float4*)&sz[n][kq * 4] = zv;
    }
    __syncthreads();

    const int cg = tid & 15;
    const int ng = tid >> 4;
    float acc[4][4];

    #pragma unroll
    for (int ni = 0; ni < 4; ++ni)
        #pragma unroll
        for (int ci = 0; ci < 4; ++ci) acc[ni][ci] = sb1[cg * 4 + ci];

    #pragma unroll 4
    for (int k = 0; k < D; ++k) {
        float4 wv = *(const float4*)&sw1[k][cg * 4];
        #pragma unroll
        for (int ni = 0; ni < 4; ++ni) {
            float zv = sz[ng * 4 + ni][k];
            acc[ni][0] += zv * wv.x;
            acc[ni][1] += zv * wv.y;
            acc[ni][2] += zv * wv.z;
            acc[ni][3] += zv * wv.w;
        }
    }
    #pragma unroll
    for (int ni = 0; ni < 4; ++ni)
        #pragma unroll
        for (int ci = 0; ci < 4; ++ci) {
            float v = acc[ni][ci];
            sy[ng * 4 + ni][cg * 4 + ci] = v > 0.f ? v : 0.f;
        }
    __syncthreads();

    #pragma unroll
    for (int ni = 0; ni < 4; ++ni)
        #pragma unroll
        for (int ci = 0; ci < 4; ++ci) acc[ni][ci] = sb2[cg * 4 + ci];

    #pragma unroll 4
    for (int k = 0; k < D; ++k) {
        float4 wv = *(const float4*)&sw2[k][cg * 4];
        #pragma unroll
        for (int ni = 0; ni < 4; ++ni) {
            float yv = sy[ng * 4 + ni][k];
            acc[ni][0] += yv * wv.x;
            acc[ni][1] += yv * wv.y;
            acc[ni][2] += yv * wv.z;
            acc[ni][3] += yv * wv.w;
        }
    }
    #pragma unroll
    for (int ni = 0; ni < 4; ++ni) {
        float4 o;
        o.x = acc[ni][0]; o.y = acc[ni][1]; o.z = acc[ni][2]; o.w = acc[ni][3];
        if (FINAL_RELU) {
            o.x = o.x > 0.f ? o.x : 0.f;
            o.y = o.y > 0.f ? o.y : 0.f;
            o.z = o.z > 0.f ? o.z : 0.f;
            o.w = o.w > 0.f ? o.w : 0.f;
        }
        *(float4*)(Out + (nbase + ng * 4 + ni) * D + cg * 4) = o;
    }
}

// ================= pooling =================
__global__ __launch_bounds__(256) void k_init_pool(float* __restrict__ psum,
                                                   float* __restrict__ pmax) {
    int t = blockIdx.x * blockDim.x + threadIdx.x;
    if (t < NGRAPH * D) {
        psum[t] = 0.f;
        pmax[t] = -INFINITY;
    }
}

__device__ inline void atomicMaxFloat(float* addr, float val) {
    if (val >= 0.f) atomicMax((int*)addr, __float_as_int(val));
    else            atomicMin((unsigned int*)addr, __float_as_uint(val));
}

__global__ __launch_bounds__(256) void k_pool(const float* __restrict__ H,
                                              const int* __restrict__ batch,
                                              float* __restrict__ psum,
                                              float* __restrict__ pmax) {
    long gt = (long)blockIdx.x * blockDim.x + threadIdx.x;
    int wave = (int)(gt >> 6);
    int lane = (int)(gt & 63);
    int n0 = wave * 16;
    if (n0 >= N_NODES) return;
    int curg = batch[n0];
    float accs = 0.f;
    float accm = -INFINITY;
    #pragma unroll 4
    for (int i = 0; i < 16; ++i) {
        int n = n0 + i;
        if (n >= N_NODES) break;
        int g = batch[n];
        if (g != curg) {
            atomicAdd(&psum[curg * D + lane], accs);
            atomicMaxFloat(&pmax[curg * D + lane], accm);
            accs = 0.f; accm = -INFINITY; curg = g;
        }
        float v = H[(long)n * D + lane];
        accs += v;
        accm = accm > v ? accm : v;
    }
    atomicAdd(&psum[curg * D + lane], accs);
    atomicMaxFloat(&pmax[curg * D + lane], accm);
}

// ================= MLP head =================
__device__ inline float silu(float x) { return x / (1.f + expf(-x)); }

__global__ __launch_bounds__(128) void k_head(
    const float* __restrict__ psum, const float* __restrict__ pmax,
    const float* __restrict__ w0, const float* __restrict__ b0,
    const float* __restrict__ w1, const float* __restrict__ b1,
    const float* __restrict__ w2, const float* __restrict__ b2,
    const float* __restrict__ w3, const float* __restrict__ b3,
    const float* __restrict__ w4, const float* __restrict__ b4,
    float* __restrict__ out)
{
    __shared__ float bufA[128];
    __shared__ float bufB[128];
    int g = blockIdx.x, t = threadIdx.x;
    bufA[t] = (t < 64) ? psum[g * 64 + t] : pmax[g * 64 + (t - 64)];
    __syncthreads();
    {
        float a = b0[t];
        for (int k = 0; k < 128; ++k) a += bufA[k] * w0[k * 128 + t];
        bufB[t] = silu(a);
    }
    __syncthreads();
    if (t < 64) {
        float a = b1[t];
        for (int k = 0; k < 128; ++k) a += bufB[k] * w1[k * 64 + t];
        bufA[t] = silu(a);
    }
    __syncthreads();
    if (t < 32) {
        float a = b2[t];
        for (int k = 0; k < 64; ++k) a += bufA[k] * w2[k * 32 + t];
        bufB[t] = silu(a);
    }
    __syncthreads();
    if (t < 16) {
        float a = b3[t];
        for (int k = 0; k < 32; ++k) a += bufB[k] * w3[k * 16 + t];
        bufA[t] = silu(a);
    }
    __syncthreads();
    if (t == 0) {
        float a = b4[0];
        for (int k = 0; k < 16; ++k) a += bufA[k] * w4[k];
        out[g] = a;
    }
}

extern "C" void kernel_launch(void* const* d_in, const int* in_sizes, int n_in,
                              void* d_out, int out_size, void* d_ws, size_t ws_size,
                              hipStream_t stream) {
    const float* x     = (const float*)d_in[0];
    const int*   ei    = (const int*)d_in[1];
    const int*   batch = (const int*)d_in[2];
    const float* c1w1 = (const float*)d_in[3];
    const float* c1b1 = (const float*)d_in[4];
    const float* c1w2 = (const float*)d_in[5];
    const float* c1b2 = (const float*)d_in[6];
    const float* c2w1 = (const float*)d_in[7];
    const float* c2b1 = (const float*)d_in[8];
    const float* c2w2 = (const float*)d_in[9];
    const float* c2b2 = (const float*)d_in[10];
    const float* hw0 = (const float*)d_in[11];
    const float* hb0 = (const float*)d_in[12];
    const float* hw1 = (const float*)d_in[13];
    const float* hb1 = (const float*)d_in[14];
    const float* hw2 = (const float*)d_in[15];
    const float* hb2 = (const float*)d_in[16];
    const float* hw3 = (const float*)d_in[17];
    const float* hb3 = (const float*)d_in[18];
    const float* hw4 = (const float*)d_in[19];
    const float* hb4 = (const float*)d_in[20];

    float* A    = (float*)d_ws;                         // 51.2 MB
    float* H    = A + (size_t)N_NODES * D;              // 51.2 MB
    float* psum = H + (size_t)N_NODES * D;              // 32 KB
    float* pmax = psum + NGRAPH * D;                    // 32 KB
    int* rowptr = (int*)(pmax + NGRAPH * D);            // N_NODES+1
    int* cursor = rowptr + (N_NODES + 4);               // N_NODES
    int* blksum = cursor + N_NODES;                     // 256
    int* csr    = blksum + 256;                         // N_EDGES
    float* out  = (float*)d_out;

    const int* srcs = ei;
    const int* dsts = ei + N_EDGES;

    const int edgeBlocks = (N_EDGES + 255) / 256;       // 4883
    const int scanBlocks = (N_NODES + 1023) / 1024;     // 196
    const int aggBlocks  = (N_NODES * 64) / 256;        // 50000
    const int mlpBlocks  = N_NODES / 64;                // 3125
    const int poolBlocks = N_NODES / 64;                // 3125

    // ---- CSR build (once, by dst) ----
    hipMemsetAsync(rowptr, 0, (N_NODES + 4) * sizeof(int), stream);
    k_hist <<<edgeBlocks, 256, 0, stream>>>(dsts, rowptr);
    k_scan1<<<scanBlocks, 256, 0, stream>>>(rowptr, blksum, N_NODES);
    k_scan2<<<1,          256, 0, stream>>>(blksum, scanBlocks);
    k_scan3<<<scanBlocks, 256, 0, stream>>>(rowptr, blksum, cursor, N_NODES);
    k_fill <<<edgeBlocks, 256, 0, stream>>>(srcs, dsts, cursor, csr);

    // ---- conv1 ----
    k_agg    <<<aggBlocks, 256, 0, stream>>>(x, rowptr, csr, A);
    k_gin_mlp<1><<<mlpBlocks, 256, 0, stream>>>(x, A, c1w1, c1b1, c1w2, c1b2, H);

    // ---- conv2 ----
    k_agg    <<<aggBlocks, 256, 0, stream>>>(H, rowptr, csr, A);
    k_gin_mlp<0><<<mlpBlocks, 256, 0, stream>>>(H, A, c2w1, c2b1, c2w2, c2b2, H);

    // ---- pooling ----
    k_init_pool<<<(NGRAPH * D + 255) / 256, 256, 0, stream>>>(psum, pmax);
    k_pool<<<poolBlocks, 256, 0, stream>>>(H, batch, psum, pmax);

    // ---- head ----
    k_head<<<NGRAPH, 128, 0, stream>>>(psum, pmax,
                                       hw0, hb0, hw1, hb1, hw2, hb2, hw3, hb3, hw4, hb4,
                                       out);
}

// Round 3
// 358.876 us; speedup vs baseline: 1.9923x; 1.3394x over previous
//
#include <hip/hip_runtime.h>
#include <math.h>

#define N_NODES  200000
#define N_EDGES  1250000
#define D        64
#define NGRAPH   128
#define ZSTR     68   // padded LDS row stride (floats)

typedef unsigned int uint;
typedef unsigned short ushort;

// RNE pack of one float to bf16 bits
__device__ inline uint bf1(float a) {
    uint u = __float_as_uint(a);
    return (u + 0x7fffu + ((u >> 16) & 1u)) >> 16;
}
__device__ inline float ubf_lo(uint u) { return __uint_as_float(u << 16); }
__device__ inline float ubf_hi(uint u) { return __uint_as_float(u & 0xffff0000u); }

// ================= CSR build =================
__global__ __launch_bounds__(256) void k_hist(const int* __restrict__ dsts,
                                              int* __restrict__ deg) {
    int e = blockIdx.x * 256 + threadIdx.x;
    if (e < N_EDGES) atomicAdd(&deg[dsts[e]], 1);
}

__global__ __launch_bounds__(256) void k_scan1(int* __restrict__ data,
                                               int* __restrict__ blksum, int n) {
    __shared__ int s[256];
    int tid = threadIdx.x;
    int base = blockIdx.x * 1024 + tid * 4;
    int v0 = (base + 0 < n) ? data[base + 0] : 0;
    int v1 = (base + 1 < n) ? data[base + 1] : 0;
    int v2 = (base + 2 < n) ? data[base + 2] : 0;
    int v3 = (base + 3 < n) ? data[base + 3] : 0;
    int tsum = v0 + v1 + v2 + v3;
    s[tid] = tsum;
    __syncthreads();
    for (int off = 1; off < 256; off <<= 1) {
        int t = (tid >= off) ? s[tid - off] : 0;
        __syncthreads();
        s[tid] += t;
        __syncthreads();
    }
    int ex = s[tid] - tsum;
    if (base + 0 < n) data[base + 0] = ex;            ex += v0;
    if (base + 1 < n) data[base + 1] = ex;            ex += v1;
    if (base + 2 < n) data[base + 2] = ex;            ex += v2;
    if (base + 3 < n) data[base + 3] = ex;
    if (tid == 255) blksum[blockIdx.x] = s[255];
}

__global__ __launch_bounds__(256) void k_scan2(int* __restrict__ blksum, int nblk) {
    __shared__ int s[256];
    int tid = threadIdx.x;
    int v = (tid < nblk) ? blksum[tid] : 0;
    s[tid] = v;
    __syncthreads();
    for (int off = 1; off < 256; off <<= 1) {
        int t = (tid >= off) ? s[tid - off] : 0;
        __syncthreads();
        s[tid] += t;
        __syncthreads();
    }
    if (tid < nblk) blksum[tid] = s[tid] - v;
}

__global__ __launch_bounds__(256) void k_scan3(int* __restrict__ rowptr,
                                               const int* __restrict__ blksum,
                                               int* __restrict__ cursor, int n) {
    int base = blockIdx.x * 1024 + threadIdx.x * 4;
    int off = blksum[blockIdx.x];
    #pragma unroll
    for (int j = 0; j < 4; ++j) {
        int i = base + j;
        if (i < n) {
            int r = rowptr[i] + off;
            rowptr[i] = r;
            cursor[i] = r;
        }
    }
    if (blockIdx.x == 0 && threadIdx.x == 0) rowptr[n] = N_EDGES;
}

__global__ __launch_bounds__(256) void k_fill(const int* __restrict__ srcs,
                                              const int* __restrict__ dsts,
                                              int* __restrict__ cursor,
                                              int* __restrict__ csr) {
    int e = blockIdx.x * 256 + threadIdx.x;
    if (e < N_EDGES) {
        int d = dsts[e];
        int pos = atomicAdd(&cursor[d], 1);
        csr[pos] = srcs[e];
    }
}

// ================= fp32 -> bf16 cast (RNE) =================
__global__ __launch_bounds__(256) void k_cast(const float* __restrict__ in,
                                              ushort* __restrict__ outb) {
    int t = blockIdx.x * 256 + threadIdx.x;   // 8 floats per thread
    long base = (long)t * 8;
    float4 a = *(const float4*)(in + base);
    float4 b = *(const float4*)(in + base + 4);
    uint4 o;
    o.x = bf1(a.x) | (bf1(a.y) << 16);
    o.y = bf1(a.z) | (bf1(a.w) << 16);
    o.z = bf1(b.x) | (bf1(b.y) << 16);
    o.w = bf1(b.z) | (bf1(b.w) << 16);
    *(uint4*)(outb + base) = o;
}

// ================= fused GIN conv: gather(bf16) + self(fp32) + 2-layer MLP ====
// Out = [relu](relu((Self + sum_nbr Gb)@w1+b1)@w2+b2), optional bf16 mirror out
template<int FINAL_RELU, int WRITE_BF16>
__global__ __launch_bounds__(512, 2) void k_gin_fused(
    const float* __restrict__ Self, const ushort* __restrict__ Gb,
    const int* __restrict__ rowptr, const int* __restrict__ csr,
    const float* __restrict__ w1g, const float* __restrict__ b1g,
    const float* __restrict__ w2g, const float* __restrict__ b2g,
    float* __restrict__ OutF, ushort* __restrict__ OutB)
{
    __shared__ float sw1[D][D];
    __shared__ float sw2[D][D];
    __shared__ float sz[D][ZSTR];
    __shared__ float sy[D][ZSTR];
    __shared__ float sb1[D], sb2[D];
    const int tid = threadIdx.x;
    const long nbase = (long)blockIdx.x * 64;

    // stage weights: 1024 float4 each, 512 threads -> 2 apiece
    #pragma unroll
    for (int i = 0; i < 2; ++i) {
        int f = tid + i * 512;
        ((float4*)sw1)[f] = ((const float4*)w1g)[f];
        ((float4*)sw2)[f] = ((const float4*)w2g)[f];
    }
    if (tid < D) { sb1[tid] = b1g[tid]; sb2[tid] = b2g[tid]; }

    // ---- gather phase: 8 threads per node, 8 features each ----
    {
        const int nl = tid >> 3;          // 0..63 node within block
        const int fo = (tid & 7) * 8;     // feature octet
        const long n = nbase + nl;
        float acc[8];
        float4 s0 = *(const float4*)(Self + n * D + fo);
        float4 s1 = *(const float4*)(Self + n * D + fo + 4);
        acc[0] = s0.x; acc[1] = s0.y; acc[2] = s0.z; acc[3] = s0.w;
        acc[4] = s1.x; acc[5] = s1.y; acc[6] = s1.z; acc[7] = s1.w;
        int i = rowptr[n];
        const int end = rowptr[n + 1];
        for (; i + 1 < end; i += 2) {
            int sa = csr[i];
            int sb = csr[i + 1];
            uint4 va = *(const uint4*)(Gb + ((long)sa << 6) + fo);
            uint4 vb = *(const uint4*)(Gb + ((long)sb << 6) + fo);
            acc[0] += ubf_lo(va.x); acc[1] += ubf_hi(va.x);
            acc[2] += ubf_lo(va.y); acc[3] += ubf_hi(va.y);
            acc[4] += ubf_lo(va.z); acc[5] += ubf_hi(va.z);
            acc[6] += ubf_lo(va.w); acc[7] += ubf_hi(va.w);
            acc[0] += ubf_lo(vb.x); acc[1] += ubf_hi(vb.x);
            acc[2] += ubf_lo(vb.y); acc[3] += ubf_hi(vb.y);
            acc[4] += ubf_lo(vb.z); acc[5] += ubf_hi(vb.z);
            acc[6] += ubf_lo(vb.w); acc[7] += ubf_hi(vb.w);
        }
        if (i < end) {
            int sa = csr[i];
            uint4 va = *(const uint4*)(Gb + ((long)sa << 6) + fo);
            acc[0] += ubf_lo(va.x); acc[1] += ubf_hi(va.x);
            acc[2] += ubf_lo(va.y); acc[3] += ubf_hi(va.y);
            acc[4] += ubf_lo(va.z); acc[5] += ubf_hi(va.z);
            acc[6] += ubf_lo(va.w); acc[7] += ubf_hi(va.w);
        }
        float4 z0 = make_float4(acc[0], acc[1], acc[2], acc[3]);
        float4 z1 = make_float4(acc[4], acc[5], acc[6], acc[7]);
        *(float4*)&sz[nl][fo]     = z0;
        *(float4*)&sz[nl][fo + 4] = z1;
    }
    __syncthreads();

    // ---- MLP: 512 threads = 16 colgroups x 32 nodegroups (2 nodes each) ----
    const int cg = tid & 15;
    const int ng = tid >> 4;          // 0..31
    float acc[2][4];

    #pragma unroll
    for (int ni = 0; ni < 2; ++ni)
        #pragma unroll
        for (int ci = 0; ci < 4; ++ci) acc[ni][ci] = sb1[cg * 4 + ci];

    #pragma unroll 4
    for (int k = 0; k < D; ++k) {
        float4 wv = *(const float4*)&sw1[k][cg * 4];
        #pragma unroll
        for (int ni = 0; ni < 2; ++ni) {
            float zv = sz[ng * 2 + ni][k];
            acc[ni][0] += zv * wv.x;
            acc[ni][1] += zv * wv.y;
            acc[ni][2] += zv * wv.z;
            acc[ni][3] += zv * wv.w;
        }
    }
    #pragma unroll
    for (int ni = 0; ni < 2; ++ni) {
        float4 y;
        y.x = acc[ni][0] > 0.f ? acc[ni][0] : 0.f;
        y.y = acc[ni][1] > 0.f ? acc[ni][1] : 0.f;
        y.z = acc[ni][2] > 0.f ? acc[ni][2] : 0.f;
        y.w = acc[ni][3] > 0.f ? acc[ni][3] : 0.f;
        *(float4*)&sy[ng * 2 + ni][cg * 4] = y;
    }
    __syncthreads();

    #pragma unroll
    for (int ni = 0; ni < 2; ++ni)
        #pragma unroll
        for (int ci = 0; ci < 4; ++ci) acc[ni][ci] = sb2[cg * 4 + ci];

    #pragma unroll 4
    for (int k = 0; k < D; ++k) {
        float4 wv = *(const float4*)&sw2[k][cg * 4];
        #pragma unroll
        for (int ni = 0; ni < 2; ++ni) {
            float yv = sy[ng * 2 + ni][k];
            acc[ni][0] += yv * wv.x;
            acc[ni][1] += yv * wv.y;
            acc[ni][2] += yv * wv.z;
            acc[ni][3] += yv * wv.w;
        }
    }
    #pragma unroll
    for (int ni = 0; ni < 2; ++ni) {
        float4 o;
        o.x = acc[ni][0]; o.y = acc[ni][1]; o.z = acc[ni][2]; o.w = acc[ni][3];
        if (FINAL_RELU) {
            o.x = o.x > 0.f ? o.x : 0.f;
            o.y = o.y > 0.f ? o.y : 0.f;
            o.z = o.z > 0.f ? o.z : 0.f;
            o.w = o.w > 0.f ? o.w : 0.f;
        }
        long node = nbase + ng * 2 + ni;
        *(float4*)(OutF + node * D + cg * 4) = o;
        if (WRITE_BF16) {
            uint2 p;
            p.x = bf1(o.x) | (bf1(o.y) << 16);
            p.y = bf1(o.z) | (bf1(o.w) << 16);
            *(uint2*)(OutB + node * D + cg * 4) = p;
        }
    }
}

// ================= pooling =================
__global__ __launch_bounds__(256) void k_init_pool(float* __restrict__ psum,
                                                   float* __restrict__ pmax) {
    int t = blockIdx.x * blockDim.x + threadIdx.x;
    if (t < NGRAPH * D) {
        psum[t] = 0.f;
        pmax[t] = -INFINITY;
    }
}

__device__ inline void atomicMaxFloat(float* addr, float val) {
    if (val >= 0.f) atomicMax((int*)addr, __float_as_int(val));
    else            atomicMin((unsigned int*)addr, __float_as_uint(val));
}

__global__ __launch_bounds__(256) void k_pool(const float* __restrict__ H,
                                              const int* __restrict__ batch,
                                              float* __restrict__ psum,
                                              float* __restrict__ pmax) {
    long gt = (long)blockIdx.x * blockDim.x + threadIdx.x;
    int wave = (int)(gt >> 6);
    int lane = (int)(gt & 63);
    int n0 = wave * 16;
    if (n0 >= N_NODES) return;
    int curg = batch[n0];
    float accs = 0.f;
    float accm = -INFINITY;
    #pragma unroll 4
    for (int i = 0; i < 16; ++i) {
        int n = n0 + i;
        if (n >= N_NODES) break;
        int g = batch[n];
        if (g != curg) {
            atomicAdd(&psum[curg * D + lane], accs);
            atomicMaxFloat(&pmax[curg * D + lane], accm);
            accs = 0.f; accm = -INFINITY; curg = g;
        }
        float v = H[(long)n * D + lane];
        accs += v;
        accm = accm > v ? accm : v;
    }
    atomicAdd(&psum[curg * D + lane], accs);
    atomicMaxFloat(&pmax[curg * D + lane], accm);
}

// ================= MLP head =================
__device__ inline float silu(float x) { return x / (1.f + expf(-x)); }

__global__ __launch_bounds__(128) void k_head(
    const float* __restrict__ psum, const float* __restrict__ pmax,
    const float* __restrict__ w0, const float* __restrict__ b0,
    const float* __restrict__ w1, const float* __restrict__ b1,
    const float* __restrict__ w2, const float* __restrict__ b2,
    const float* __restrict__ w3, const float* __restrict__ b3,
    const float* __restrict__ w4, const float* __restrict__ b4,
    float* __restrict__ out)
{
    __shared__ float bufA[128];
    __shared__ float bufB[128];
    int g = blockIdx.x, t = threadIdx.x;
    bufA[t] = (t < 64) ? psum[g * 64 + t] : pmax[g * 64 + (t - 64)];
    __syncthreads();
    {
        float a = b0[t];
        for (int k = 0; k < 128; ++k) a += bufA[k] * w0[k * 128 + t];
        bufB[t] = silu(a);
    }
    __syncthreads();
    if (t < 64) {
        float a = b1[t];
        for (int k = 0; k < 128; ++k) a += bufB[k] * w1[k * 64 + t];
        bufA[t] = silu(a);
    }
    __syncthreads();
    if (t < 32) {
        float a = b2[t];
        for (int k = 0; k < 64; ++k) a += bufA[k] * w2[k * 32 + t];
        bufB[t] = silu(a);
    }
    __syncthreads();
    if (t < 16) {
        float a = b3[t];
        for (int k = 0; k < 32; ++k) a += bufB[k] * w3[k * 16 + t];
        bufA[t] = silu(a);
    }
    __syncthreads();
    if (t == 0) {
        float a = b4[0];
        for (int k = 0; k < 16; ++k) a += bufA[k] * w4[k];
        out[g] = a;
    }
}

extern "C" void kernel_launch(void* const* d_in, const int* in_sizes, int n_in,
                              void* d_out, int out_size, void* d_ws, size_t ws_size,
                              hipStream_t stream) {
    const float* x     = (const float*)d_in[0];
    const int*   ei    = (const int*)d_in[1];
    const int*   batch = (const int*)d_in[2];
    const float* c1w1 = (const float*)d_in[3];
    const float* c1b1 = (const float*)d_in[4];
    const float* c1w2 = (const float*)d_in[5];
    const float* c1b2 = (const float*)d_in[6];
    const float* c2w1 = (const float*)d_in[7];
    const float* c2b1 = (const float*)d_in[8];
    const float* c2w2 = (const float*)d_in[9];
    const float* c2b2 = (const float*)d_in[10];
    const float* hw0 = (const float*)d_in[11];
    const float* hb0 = (const float*)d_in[12];
    const float* hw1 = (const float*)d_in[13];
    const float* hb1 = (const float*)d_in[14];
    const float* hw2 = (const float*)d_in[15];
    const float* hb2 = (const float*)d_in[16];
    const float* hw3 = (const float*)d_in[17];
    const float* hb3 = (const float*)d_in[18];
    const float* hw4 = (const float*)d_in[19];
    const float* hb4 = (const float*)d_in[20];

    const size_t NF = (size_t)N_NODES * D;              // 12.8M elems
    float*  H    = (float*)d_ws;                        // 51.2 MB (conv1 out, conv2 in-place out)
    ushort* xb   = (ushort*)(H + NF);                   // 25.6 MB bf16 x
    ushort* hb   = xb + NF;                             // 25.6 MB bf16 conv1 out
    float*  psum = (float*)(hb + NF);
    float*  pmax = psum + NGRAPH * D;
    int* rowptr  = (int*)(pmax + NGRAPH * D);           // N_NODES+1 (+pad)
    int* cursor  = rowptr + (N_NODES + 4);
    int* blksum  = cursor + N_NODES;
    int* csr     = blksum + 256;                        // N_EDGES
    float* out   = (float*)d_out;

    const int* srcs = ei;
    const int* dsts = ei + N_EDGES;

    const int edgeBlocks = (N_EDGES + 255) / 256;       // 4883
    const int scanBlocks = (N_NODES + 1023) / 1024;     // 196
    const int convBlocks = N_NODES / 64;                // 3125
    const int castBlocks = (int)(NF / (256 * 8));       // 6250
    const int poolBlocks = N_NODES / 64;                // 3125

    // ---- CSR build (by dst) ----
    hipMemsetAsync(rowptr, 0, (N_NODES + 4) * sizeof(int), stream);
    k_hist <<<edgeBlocks, 256, 0, stream>>>(dsts, rowptr);
    k_scan1<<<scanBlocks, 256, 0, stream>>>(rowptr, blksum, N_NODES);
    k_scan2<<<1,          256, 0, stream>>>(blksum, scanBlocks);
    k_scan3<<<scanBlocks, 256, 0, stream>>>(rowptr, blksum, cursor, N_NODES);
    k_fill <<<edgeBlocks, 256, 0, stream>>>(srcs, dsts, cursor, csr);

    // ---- bf16 copy of x ----
    k_cast<<<castBlocks, 256, 0, stream>>>(x, xb);

    // ---- conv1: self=x(fp32), gather=xb(bf16) -> H(fp32) + hb(bf16) ----
    k_gin_fused<1, 1><<<convBlocks, 512, 0, stream>>>(
        x, xb, rowptr, csr, c1w1, c1b1, c1w2, c1b2, H, hb);

    // ---- conv2: self=H(fp32), gather=hb(bf16) -> H in place ----
    k_gin_fused<0, 0><<<convBlocks, 512, 0, stream>>>(
        H, hb, rowptr, csr, c2w1, c2b1, c2w2, c2b2, H, (ushort*)nullptr);

    // ---- pooling ----
    k_init_pool<<<(NGRAPH * D + 255) / 256, 256, 0, stream>>>(psum, pmax);
    k_pool<<<poolBlocks, 256, 0, stream>>>(H, batch, psum, pmax);

    // ---- head ----
    k_head<<<NGRAPH, 128, 0, stream>>>(psum, pmax,
                                       hw0, hb0, hw1, hb1, hw2, hb2, hw3, hb3, hw4, hb4,
                                       out);
}

// Round 4
// 336.019 us; speedup vs baseline: 2.1278x; 1.0680x over previous
//
#include <hip/hip_runtime.h>
#include <math.h>

#define N_NODES  200000
#define N_EDGES  1250000
#define D        64
#define NGRAPH   128
#define ZSTR     68   // padded LDS row stride (floats)

#define BKT   196     // dst buckets: dst>>10, 200000>>10 = 195 -> 196 buckets
#define BSH   10
#define BCAP  8192    // slots per bucket (mean 6400, sigma ~80)

typedef unsigned int uint;
typedef unsigned short ushort;

// RNE pack of one float to bf16 bits
__device__ inline uint bf1(float a) {
    uint u = __float_as_uint(a);
    return (u + 0x7fffu + ((u >> 16) & 1u)) >> 16;
}
__device__ inline float ubf_lo(uint u) { return __uint_as_float(u << 16); }
__device__ inline float ubf_hi(uint u) { return __uint_as_float(u & 0xffff0000u); }

// ================= CSR build =================
__global__ __launch_bounds__(256) void k_hist(const int* __restrict__ dsts,
                                              int* __restrict__ deg) {
    int e = blockIdx.x * 256 + threadIdx.x;
    if (e < N_EDGES) atomicAdd(&deg[dsts[e]], 1);
}

__global__ __launch_bounds__(256) void k_scan1(int* __restrict__ data,
                                               int* __restrict__ blksum, int n) {
    __shared__ int s[256];
    int tid = threadIdx.x;
    int base = blockIdx.x * 1024 + tid * 4;
    int v0 = (base + 0 < n) ? data[base + 0] : 0;
    int v1 = (base + 1 < n) ? data[base + 1] : 0;
    int v2 = (base + 2 < n) ? data[base + 2] : 0;
    int v3 = (base + 3 < n) ? data[base + 3] : 0;
    int tsum = v0 + v1 + v2 + v3;
    s[tid] = tsum;
    __syncthreads();
    for (int off = 1; off < 256; off <<= 1) {
        int t = (tid >= off) ? s[tid - off] : 0;
        __syncthreads();
        s[tid] += t;
        __syncthreads();
    }
    int ex = s[tid] - tsum;
    if (base + 0 < n) data[base + 0] = ex;            ex += v0;
    if (base + 1 < n) data[base + 1] = ex;            ex += v1;
    if (base + 2 < n) data[base + 2] = ex;            ex += v2;
    if (base + 3 < n) data[base + 3] = ex;
    if (tid == 255) blksum[blockIdx.x] = s[255];
}

__global__ __launch_bounds__(256) void k_scan2(int* __restrict__ blksum, int nblk) {
    __shared__ int s[256];
    int tid = threadIdx.x;
    int v = (tid < nblk) ? blksum[tid] : 0;
    s[tid] = v;
    __syncthreads();
    for (int off = 1; off < 256; off <<= 1) {
        int t = (tid >= off) ? s[tid - off] : 0;
        __syncthreads();
        s[tid] += t;
        __syncthreads();
    }
    if (tid < nblk) blksum[tid] = s[tid] - v;
}

__global__ __launch_bounds__(256) void k_scan3(int* __restrict__ rowptr,
                                               const int* __restrict__ blksum,
                                               int* __restrict__ cursor, int n) {
    int base = blockIdx.x * 1024 + threadIdx.x * 4;
    int off = blksum[blockIdx.x];
    #pragma unroll
    for (int j = 0; j < 4; ++j) {
        int i = base + j;
        if (i < n) {
            int r = rowptr[i] + off;
            rowptr[i] = r;
            cursor[i] = r;
        }
    }
    if (blockIdx.x == 0 && threadIdx.x == 0) rowptr[n] = N_EDGES;
}

// ---- phase A: partition edges into dst buckets, packed 4B records ----
// record = (dst & 1023) << 18 | src   (src < 2^18, dst-low 10 bits)
__global__ __launch_bounds__(256) void k_part(const int* __restrict__ srcs,
                                              const int* __restrict__ dsts,
                                              int* __restrict__ gcur,
                                              uint* __restrict__ recs) {
    __shared__ int lhist[BKT];
    __shared__ int lbase[BKT];
    const int tid = threadIdx.x;
    const long ebase = (long)blockIdx.x * 4096;
    for (int i = tid; i < BKT; i += 256) lhist[i] = 0;
    __syncthreads();
    #pragma unroll
    for (int j = 0; j < 16; ++j) {
        long e = ebase + j * 256 + tid;
        if (e < N_EDGES) atomicAdd(&lhist[dsts[e] >> BSH], 1);
    }
    __syncthreads();
    for (int i = tid; i < BKT; i += 256) {
        int c = lhist[i];
        lbase[i] = c > 0 ? atomicAdd(&gcur[i], c) : 0;
        lhist[i] = 0;
    }
    __syncthreads();
    #pragma unroll
    for (int j = 0; j < 16; ++j) {
        long e = ebase + j * 256 + tid;
        if (e < N_EDGES) {
            int d = dsts[e];
            int s = srcs[e];
            int b = d >> BSH;
            int r = atomicAdd(&lhist[b], 1);
            recs[(long)b * BCAP + lbase[b] + r] = ((uint)(d & 1023) << 18) | (uint)s;
        }
    }
}

// ---- phase B: per-bucket replay; cursor/csr windows are L2-resident ----
__global__ __launch_bounds__(256) void k_fill2(const uint* __restrict__ recs,
                                               const int* __restrict__ gcur,
                                               int* __restrict__ cursor,
                                               int* __restrict__ csr) {
    int b = blockIdx.x >> 1;
    int half = blockIdx.x & 1;
    int cnt = gcur[b];
    int dbase = b << BSH;
    for (int i = half * 256 + threadIdx.x; i < cnt; i += 512) {
        uint rec = recs[(long)b * BCAP + i];
        int d = dbase + (int)(rec >> 18);
        int s = (int)(rec & 0x3FFFFu);
        int pos = atomicAdd(&cursor[d], 1);
        csr[pos] = s;
    }
}

// ================= fp32 -> bf16 cast (RNE) =================
__global__ __launch_bounds__(256) void k_cast(const float* __restrict__ in,
                                              ushort* __restrict__ outb) {
    int t = blockIdx.x * 256 + threadIdx.x;   // 8 floats per thread
    long base = (long)t * 8;
    float4 a = *(const float4*)(in + base);
    float4 b = *(const float4*)(in + base + 4);
    uint4 o;
    o.x = bf1(a.x) | (bf1(a.y) << 16);
    o.y = bf1(a.z) | (bf1(a.w) << 16);
    o.z = bf1(b.x) | (bf1(b.y) << 16);
    o.w = bf1(b.z) | (bf1(b.w) << 16);
    *(uint4*)(outb + base) = o;
}

// ================= fused GIN conv =================
template<int FINAL_RELU, int WRITE_BF16>
__global__ __launch_bounds__(512, 2) void k_gin_fused(
    const float* __restrict__ Self, const ushort* __restrict__ Gb,
    const int* __restrict__ rowptr, const int* __restrict__ csr,
    const float* __restrict__ w1g, const float* __restrict__ b1g,
    const float* __restrict__ w2g, const float* __restrict__ b2g,
    float* __restrict__ OutF, ushort* __restrict__ OutB)
{
    __shared__ float sw1[D][D];
    __shared__ float sw2[D][D];
    __shared__ float sz[D][ZSTR];
    __shared__ float sy[D][ZSTR];
    __shared__ float sb1[D], sb2[D];
    const int tid = threadIdx.x;
    const long nbase = (long)blockIdx.x * 64;

    #pragma unroll
    for (int i = 0; i < 2; ++i) {
        int f = tid + i * 512;
        ((float4*)sw1)[f] = ((const float4*)w1g)[f];
        ((float4*)sw2)[f] = ((const float4*)w2g)[f];
    }
    if (tid < D) { sb1[tid] = b1g[tid]; sb2[tid] = b2g[tid]; }

    // ---- gather phase: 8 threads per node, 8 features each ----
    {
        const int nl = tid >> 3;
        const int fo = (tid & 7) * 8;
        const long n = nbase + nl;
        float acc[8];
        float4 s0 = *(const float4*)(Self + n * D + fo);
        float4 s1 = *(const float4*)(Self + n * D + fo + 4);
        acc[0] = s0.x; acc[1] = s0.y; acc[2] = s0.z; acc[3] = s0.w;
        acc[4] = s1.x; acc[5] = s1.y; acc[6] = s1.z; acc[7] = s1.w;
        int i = rowptr[n];
        const int end = rowptr[n + 1];
        for (; i + 1 < end; i += 2) {
            int sa = csr[i];
            int sb = csr[i + 1];
            uint4 va = *(const uint4*)(Gb + ((long)sa << 6) + fo);
            uint4 vb = *(const uint4*)(Gb + ((long)sb << 6) + fo);
            acc[0] += ubf_lo(va.x); acc[1] += ubf_hi(va.x);
            acc[2] += ubf_lo(va.y); acc[3] += ubf_hi(va.y);
            acc[4] += ubf_lo(va.z); acc[5] += ubf_hi(va.z);
            acc[6] += ubf_lo(va.w); acc[7] += ubf_hi(va.w);
            acc[0] += ubf_lo(vb.x); acc[1] += ubf_hi(vb.x);
            acc[2] += ubf_lo(vb.y); acc[3] += ubf_hi(vb.y);
            acc[4] += ubf_lo(vb.z); acc[5] += ubf_hi(vb.z);
            acc[6] += ubf_lo(vb.w); acc[7] += ubf_hi(vb.w);
        }
        if (i < end) {
            int sa = csr[i];
            uint4 va = *(const uint4*)(Gb + ((long)sa << 6) + fo);
            acc[0] += ubf_lo(va.x); acc[1] += ubf_hi(va.x);
            acc[2] += ubf_lo(va.y); acc[3] += ubf_hi(va.y);
            acc[4] += ubf_lo(va.z); acc[5] += ubf_hi(va.z);
            acc[6] += ubf_lo(va.w); acc[7] += ubf_hi(va.w);
        }
        *(float4*)&sz[nl][fo]     = make_float4(acc[0], acc[1], acc[2], acc[3]);
        *(float4*)&sz[nl][fo + 4] = make_float4(acc[4], acc[5], acc[6], acc[7]);
    }
    __syncthreads();

    const int cg = tid & 15;
    const int ng = tid >> 4;
    float acc[2][4];

    #pragma unroll
    for (int ni = 0; ni < 2; ++ni)
        #pragma unroll
        for (int ci = 0; ci < 4; ++ci) acc[ni][ci] = sb1[cg * 4 + ci];

    #pragma unroll 4
    for (int k = 0; k < D; ++k) {
        float4 wv = *(const float4*)&sw1[k][cg * 4];
        #pragma unroll
        for (int ni = 0; ni < 2; ++ni) {
            float zv = sz[ng * 2 + ni][k];
            acc[ni][0] += zv * wv.x;
            acc[ni][1] += zv * wv.y;
            acc[ni][2] += zv * wv.z;
            acc[ni][3] += zv * wv.w;
        }
    }
    #pragma unroll
    for (int ni = 0; ni < 2; ++ni) {
        float4 y;
        y.x = acc[ni][0] > 0.f ? acc[ni][0] : 0.f;
        y.y = acc[ni][1] > 0.f ? acc[ni][1] : 0.f;
        y.z = acc[ni][2] > 0.f ? acc[ni][2] : 0.f;
        y.w = acc[ni][3] > 0.f ? acc[ni][3] : 0.f;
        *(float4*)&sy[ng * 2 + ni][cg * 4] = y;
    }
    __syncthreads();

    #pragma unroll
    for (int ni = 0; ni < 2; ++ni)
        #pragma unroll
        for (int ci = 0; ci < 4; ++ci) acc[ni][ci] = sb2[cg * 4 + ci];

    #pragma unroll 4
    for (int k = 0; k < D; ++k) {
        float4 wv = *(const float4*)&sw2[k][cg * 4];
        #pragma unroll
        for (int ni = 0; ni < 2; ++ni) {
            float yv = sy[ng * 2 + ni][k];
            acc[ni][0] += yv * wv.x;
            acc[ni][1] += yv * wv.y;
            acc[ni][2] += yv * wv.z;
            acc[ni][3] += yv * wv.w;
        }
    }
    #pragma unroll
    for (int ni = 0; ni < 2; ++ni) {
        float4 o;
        o.x = acc[ni][0]; o.y = acc[ni][1]; o.z = acc[ni][2]; o.w = acc[ni][3];
        if (FINAL_RELU) {
            o.x = o.x > 0.f ? o.x : 0.f;
            o.y = o.y > 0.f ? o.y : 0.f;
            o.z = o.z > 0.f ? o.z : 0.f;
            o.w = o.w > 0.f ? o.w : 0.f;
        }
        long node = nbase + ng * 2 + ni;
        *(float4*)(OutF + node * D + cg * 4) = o;
        if (WRITE_BF16) {
            uint2 p;
            p.x = bf1(o.x) | (bf1(o.y) << 16);
            p.y = bf1(o.z) | (bf1(o.w) << 16);
            *(uint2*)(OutB + node * D + cg * 4) = p;
        }
    }
}

// ================= pooling =================
__global__ __launch_bounds__(256) void k_init_pool(float* __restrict__ psum,
                                                   float* __restrict__ pmax) {
    int t = blockIdx.x * blockDim.x + threadIdx.x;
    if (t < NGRAPH * D) {
        psum[t] = 0.f;
        pmax[t] = -INFINITY;
    }
}

__device__ inline void atomicMaxFloat(float* addr, float val) {
    if (val >= 0.f) atomicMax((int*)addr, __float_as_int(val));
    else            atomicMin((unsigned int*)addr, __float_as_uint(val));
}

__global__ __launch_bounds__(256) void k_pool(const float* __restrict__ H,
                                              const int* __restrict__ batch,
                                              float* __restrict__ psum,
                                              float* __restrict__ pmax) {
    long gt = (long)blockIdx.x * blockDim.x + threadIdx.x;
    int wave = (int)(gt >> 6);
    int lane = (int)(gt & 63);
    int n0 = wave * 16;
    if (n0 >= N_NODES) return;
    int curg = batch[n0];
    float accs = 0.f;
    float accm = -INFINITY;
    #pragma unroll 4
    for (int i = 0; i < 16; ++i) {
        int n = n0 + i;
        if (n >= N_NODES) break;
        int g = batch[n];
        if (g != curg) {
            atomicAdd(&psum[curg * D + lane], accs);
            atomicMaxFloat(&pmax[curg * D + lane], accm);
            accs = 0.f; accm = -INFINITY; curg = g;
        }
        float v = H[(long)n * D + lane];
        accs += v;
        accm = accm > v ? accm : v;
    }
    atomicAdd(&psum[curg * D + lane], accs);
    atomicMaxFloat(&pmax[curg * D + lane], accm);
}

// ================= MLP head =================
__device__ inline float silu(float x) { return x / (1.f + expf(-x)); }

__global__ __launch_bounds__(128) void k_head(
    const float* __restrict__ psum, const float* __restrict__ pmax,
    const float* __restrict__ w0, const float* __restrict__ b0,
    const float* __restrict__ w1, const float* __restrict__ b1,
    const float* __restrict__ w2, const float* __restrict__ b2,
    const float* __restrict__ w3, const float* __restrict__ b3,
    const float* __restrict__ w4, const float* __restrict__ b4,
    float* __restrict__ out)
{
    __shared__ float bufA[128];
    __shared__ float bufB[128];
    int g = blockIdx.x, t = threadIdx.x;
    bufA[t] = (t < 64) ? psum[g * 64 + t] : pmax[g * 64 + (t - 64)];
    __syncthreads();
    {
        float a = b0[t];
        for (int k = 0; k < 128; ++k) a += bufA[k] * w0[k * 128 + t];
        bufB[t] = silu(a);
    }
    __syncthreads();
    if (t < 64) {
        float a = b1[t];
        for (int k = 0; k < 128; ++k) a += bufB[k] * w1[k * 64 + t];
        bufA[t] = silu(a);
    }
    __syncthreads();
    if (t < 32) {
        float a = b2[t];
        for (int k = 0; k < 64; ++k) a += bufA[k] * w2[k * 32 + t];
        bufB[t] = silu(a);
    }
    __syncthreads();
    if (t < 16) {
        float a = b3[t];
        for (int k = 0; k < 32; ++k) a += bufB[k] * w3[k * 16 + t];
        bufA[t] = silu(a);
    }
    __syncthreads();
    if (t == 0) {
        float a = b4[0];
        for (int k = 0; k < 16; ++k) a += bufA[k] * w4[k];
        out[g] = a;
    }
}

extern "C" void kernel_launch(void* const* d_in, const int* in_sizes, int n_in,
                              void* d_out, int out_size, void* d_ws, size_t ws_size,
                              hipStream_t stream) {
    const float* x     = (const float*)d_in[0];
    const int*   ei    = (const int*)d_in[1];
    const int*   batch = (const int*)d_in[2];
    const float* c1w1 = (const float*)d_in[3];
    const float* c1b1 = (const float*)d_in[4];
    const float* c1w2 = (const float*)d_in[5];
    const float* c1b2 = (const float*)d_in[6];
    const float* c2w1 = (const float*)d_in[7];
    const float* c2b1 = (const float*)d_in[8];
    const float* c2w2 = (const float*)d_in[9];
    const float* c2b2 = (const float*)d_in[10];
    const float* hw0 = (const float*)d_in[11];
    const float* hb0 = (const float*)d_in[12];
    const float* hw1 = (const float*)d_in[13];
    const float* hb1 = (const float*)d_in[14];
    const float* hw2 = (const float*)d_in[15];
    const float* hb2 = (const float*)d_in[16];
    const float* hw3 = (const float*)d_in[17];
    const float* hb3 = (const float*)d_in[18];
    const float* hw4 = (const float*)d_in[19];
    const float* hb4 = (const float*)d_in[20];

    const size_t NF = (size_t)N_NODES * D;
    float*  H    = (float*)d_ws;                        // 51.2 MB
    ushort* xb   = (ushort*)(H + NF);                   // 25.6 MB
    ushort* hb   = xb + NF;                             // 25.6 MB
    float*  psum = (float*)(hb + NF);
    float*  pmax = psum + NGRAPH * D;
    int* rowptr  = (int*)(pmax + NGRAPH * D);           // N_NODES+4
    int* gcur    = rowptr + (N_NODES + 4);              // 256 (zeroed with rowptr)
    int* cursor  = gcur + 256;                          // N_NODES
    int* blksum  = cursor + N_NODES;                    // 256
    int* csr     = blksum + 256;                        // N_EDGES
    uint* recs   = (uint*)(csr + N_EDGES);              // BKT*BCAP = 6.4 MB
    float* out   = (float*)d_out;

    const int* srcs = ei;
    const int* dsts = ei + N_EDGES;

    const int edgeBlocks = (N_EDGES + 255) / 256;       // 4883
    const int scanBlocks = (N_NODES + 1023) / 1024;     // 196
    const int partBlocks = (N_EDGES + 4095) / 4096;     // 306
    const int convBlocks = N_NODES / 64;                // 3125
    const int castBlocks = (int)(NF / (256 * 8));       // 6250
    const int poolBlocks = N_NODES / 64;                // 3125

    // ---- CSR build (by dst) ----
    hipMemsetAsync(rowptr, 0, (N_NODES + 4 + 256) * sizeof(int), stream); // rowptr + gcur
    k_hist <<<edgeBlocks, 256, 0, stream>>>(dsts, rowptr);
    k_scan1<<<scanBlocks, 256, 0, stream>>>(rowptr, blksum, N_NODES);
    k_scan2<<<1,          256, 0, stream>>>(blksum, scanBlocks);
    k_scan3<<<scanBlocks, 256, 0, stream>>>(rowptr, blksum, cursor, N_NODES);
    k_part <<<partBlocks, 256, 0, stream>>>(srcs, dsts, gcur, recs);
    k_fill2<<<BKT * 2,    256, 0, stream>>>(recs, gcur, cursor, csr);

    // ---- bf16 copy of x ----
    k_cast<<<castBlocks, 256, 0, stream>>>(x, xb);

    // ---- conv1: self=x(fp32), gather=xb(bf16) -> H(fp32) + hb(bf16) ----
    k_gin_fused<1, 1><<<convBlocks, 512, 0, stream>>>(
        x, xb, rowptr, csr, c1w1, c1b1, c1w2, c1b2, H, hb);

    // ---- conv2: self=H(fp32), gather=hb(bf16) -> H in place ----
    k_gin_fused<0, 0><<<convBlocks, 512, 0, stream>>>(
        H, hb, rowptr, csr, c2w1, c2b1, c2w2, c2b2, H, (ushort*)nullptr);

    // ---- pooling ----
    k_init_pool<<<(NGRAPH * D + 255) / 256, 256, 0, stream>>>(psum, pmax);
    k_pool<<<poolBlocks, 256, 0, stream>>>(H, batch, psum, pmax);

    // ---- head ----
    k_head<<<NGRAPH, 128, 0, stream>>>(psum, pmax,
                                       hw0, hb0, hw1, hb1, hw2, hb2, hw3, hb3, hw4, hb4,
                                       out);
}

// Round 5
// 322.183 us; speedup vs baseline: 2.2192x; 1.0429x over previous
//
#include <hip/hip_runtime.h>
#include <math.h>

#define N_NODES  200000
#define N_EDGES  1250000
#define D        64
#define NGRAPH   128
#define ZSTR     68   // padded LDS row stride (floats)

#define BKT   196     // dst buckets: dst>>10
#define BSH   10
#define BCAP  8192

typedef unsigned int uint;
typedef unsigned short ushort;

__device__ inline uint bf1(float a) {
    uint u = __float_as_uint(a);
    return (u + 0x7fffu + ((u >> 16) & 1u)) >> 16;
}
__device__ inline float ubf_lo(uint u) { return __uint_as_float(u << 16); }
__device__ inline float ubf_hi(uint u) { return __uint_as_float(u & 0xffff0000u); }

// ================= CSR build =================
__global__ __launch_bounds__(256) void k_hist(const int* __restrict__ dsts,
                                              int* __restrict__ deg) {
    int e = blockIdx.x * 256 + threadIdx.x;
    if (e < N_EDGES) atomicAdd(&deg[dsts[e]], 1);
}

__global__ __launch_bounds__(256) void k_scan1(int* __restrict__ data,
                                               int* __restrict__ blksum, int n) {
    __shared__ int s[256];
    int tid = threadIdx.x;
    int base = blockIdx.x * 1024 + tid * 4;
    int v0 = (base + 0 < n) ? data[base + 0] : 0;
    int v1 = (base + 1 < n) ? data[base + 1] : 0;
    int v2 = (base + 2 < n) ? data[base + 2] : 0;
    int v3 = (base + 3 < n) ? data[base + 3] : 0;
    int tsum = v0 + v1 + v2 + v3;
    s[tid] = tsum;
    __syncthreads();
    for (int off = 1; off < 256; off <<= 1) {
        int t = (tid >= off) ? s[tid - off] : 0;
        __syncthreads();
        s[tid] += t;
        __syncthreads();
    }
    int ex = s[tid] - tsum;
    if (base + 0 < n) data[base + 0] = ex;            ex += v0;
    if (base + 1 < n) data[base + 1] = ex;            ex += v1;
    if (base + 2 < n) data[base + 2] = ex;            ex += v2;
    if (base + 3 < n) data[base + 3] = ex;
    if (tid == 255) blksum[blockIdx.x] = s[255];
}

__global__ __launch_bounds__(256) void k_scan2(int* __restrict__ blksum, int nblk) {
    __shared__ int s[256];
    int tid = threadIdx.x;
    int v = (tid < nblk) ? blksum[tid] : 0;
    s[tid] = v;
    __syncthreads();
    for (int off = 1; off < 256; off <<= 1) {
        int t = (tid >= off) ? s[tid - off] : 0;
        __syncthreads();
        s[tid] += t;
        __syncthreads();
    }
    if (tid < nblk) blksum[tid] = s[tid] - v;
}

__global__ __launch_bounds__(256) void k_scan3(int* __restrict__ rowptr,
                                               const int* __restrict__ blksum,
                                               int* __restrict__ cursor, int n) {
    int base = blockIdx.x * 1024 + threadIdx.x * 4;
    int off = blksum[blockIdx.x];
    #pragma unroll
    for (int j = 0; j < 4; ++j) {
        int i = base + j;
        if (i < n) {
            int r = rowptr[i] + off;
            rowptr[i] = r;
            cursor[i] = r;
        }
    }
    if (blockIdx.x == 0 && threadIdx.x == 0) rowptr[n] = N_EDGES;
}

__global__ __launch_bounds__(256) void k_part(const int* __restrict__ srcs,
                                              const int* __restrict__ dsts,
                                              int* __restrict__ gcur,
                                              uint* __restrict__ recs) {
    __shared__ int lhist[BKT];
    __shared__ int lbase[BKT];
    const int tid = threadIdx.x;
    const long ebase = (long)blockIdx.x * 4096;
    for (int i = tid; i < BKT; i += 256) lhist[i] = 0;
    __syncthreads();
    #pragma unroll
    for (int j = 0; j < 16; ++j) {
        long e = ebase + j * 256 + tid;
        if (e < N_EDGES) atomicAdd(&lhist[dsts[e] >> BSH], 1);
    }
    __syncthreads();
    for (int i = tid; i < BKT; i += 256) {
        int c = lhist[i];
        lbase[i] = c > 0 ? atomicAdd(&gcur[i], c) : 0;
        lhist[i] = 0;
    }
    __syncthreads();
    #pragma unroll
    for (int j = 0; j < 16; ++j) {
        long e = ebase + j * 256 + tid;
        if (e < N_EDGES) {
            int d = dsts[e];
            int s = srcs[e];
            int b = d >> BSH;
            int r = atomicAdd(&lhist[b], 1);
            recs[(long)b * BCAP + lbase[b] + r] = ((uint)(d & 1023) << 18) | (uint)s;
        }
    }
}

__global__ __launch_bounds__(256) void k_fill2(const uint* __restrict__ recs,
                                               const int* __restrict__ gcur,
                                               int* __restrict__ cursor,
                                               int* __restrict__ csr) {
    int b = blockIdx.x >> 1;
    int half = blockIdx.x & 1;
    int cnt = gcur[b];
    int dbase = b << BSH;
    for (int i = half * 256 + threadIdx.x; i < cnt; i += 512) {
        uint rec = recs[(long)b * BCAP + i];
        int d = dbase + (int)(rec >> 18);
        int s = (int)(rec & 0x3FFFFu);
        int pos = atomicAdd(&cursor[d], 1);
        csr[pos] = s;
    }
}

// ======== fp32 -> bf16 cast (RNE) + pool-buffer init, fused grid ========
__global__ __launch_bounds__(256) void k_cast(const float* __restrict__ in,
                                              ushort* __restrict__ outb,
                                              float* __restrict__ psum,
                                              float* __restrict__ pmax,
                                              int castBlocks) {
    if (blockIdx.x >= (uint)castBlocks) {
        int t = (blockIdx.x - castBlocks) * 256 + threadIdx.x;
        if (t < NGRAPH * D) {
            psum[t] = 0.f;
            pmax[t] = -INFINITY;
        }
        return;
    }
    int t = blockIdx.x * 256 + threadIdx.x;
    long base = (long)t * 8;
    float4 a = *(const float4*)(in + base);
    float4 b = *(const float4*)(in + base + 4);
    uint4 o;
    o.x = bf1(a.x) | (bf1(a.y) << 16);
    o.y = bf1(a.z) | (bf1(a.w) << 16);
    o.z = bf1(b.x) | (bf1(b.y) << 16);
    o.w = bf1(b.z) | (bf1(b.w) << 16);
    *(uint4*)(outb + base) = o;
}

// ================= fused GIN conv =================
// LDS slimmed to ~50 KB (sz doubles as the layer-1 activation buffer) -> 3 blocks/CU
template<int FINAL_RELU, int WRITE_BF16>
__global__ __launch_bounds__(512) void k_gin_fused(
    const float* __restrict__ Self, const ushort* __restrict__ Gb,
    const int* __restrict__ rowptr, const int* __restrict__ csr,
    const float* __restrict__ w1g, const float* __restrict__ b1g,
    const float* __restrict__ w2g, const float* __restrict__ b2g,
    float* __restrict__ OutF, ushort* __restrict__ OutB)
{
    __shared__ float sw1[D][D];
    __shared__ float sw2[D][D];
    __shared__ float sz[D][ZSTR];     // gather result, then reused for layer-1 output
    __shared__ float sb1[D], sb2[D];
    const int tid = threadIdx.x;
    const long nbase = (long)blockIdx.x * 64;

    #pragma unroll
    for (int i = 0; i < 2; ++i) {
        int f = tid + i * 512;
        ((float4*)sw1)[f] = ((const float4*)w1g)[f];
        ((float4*)sw2)[f] = ((const float4*)w2g)[f];
    }
    if (tid < D) { sb1[tid] = b1g[tid]; sb2[tid] = b2g[tid]; }

    // ---- gather phase: 8 threads per node, 8 features each; 4-edge unroll ----
    {
        const int nl = tid >> 3;
        const int fo = (tid & 7) * 8;
        const long n = nbase + nl;
        float acc[8];
        float4 s0 = *(const float4*)(Self + n * D + fo);
        float4 s1 = *(const float4*)(Self + n * D + fo + 4);
        acc[0] = s0.x; acc[1] = s0.y; acc[2] = s0.z; acc[3] = s0.w;
        acc[4] = s1.x; acc[5] = s1.y; acc[6] = s1.z; acc[7] = s1.w;
        int i = rowptr[n];
        const int end = rowptr[n + 1];
        for (; i + 3 < end; i += 4) {
            int sa = csr[i];
            int sb = csr[i + 1];
            int sc = csr[i + 2];
            int sd = csr[i + 3];
            uint4 va = *(const uint4*)(Gb + ((long)sa << 6) + fo);
            uint4 vb = *(const uint4*)(Gb + ((long)sb << 6) + fo);
            uint4 vc = *(const uint4*)(Gb + ((long)sc << 6) + fo);
            uint4 vd = *(const uint4*)(Gb + ((long)sd << 6) + fo);
            acc[0] += ubf_lo(va.x); acc[1] += ubf_hi(va.x);
            acc[2] += ubf_lo(va.y); acc[3] += ubf_hi(va.y);
            acc[4] += ubf_lo(va.z); acc[5] += ubf_hi(va.z);
            acc[6] += ubf_lo(va.w); acc[7] += ubf_hi(va.w);
            acc[0] += ubf_lo(vb.x); acc[1] += ubf_hi(vb.x);
            acc[2] += ubf_lo(vb.y); acc[3] += ubf_hi(vb.y);
            acc[4] += ubf_lo(vb.z); acc[5] += ubf_hi(vb.z);
            acc[6] += ubf_lo(vb.w); acc[7] += ubf_hi(vb.w);
            acc[0] += ubf_lo(vc.x); acc[1] += ubf_hi(vc.x);
            acc[2] += ubf_lo(vc.y); acc[3] += ubf_hi(vc.y);
            acc[4] += ubf_lo(vc.z); acc[5] += ubf_hi(vc.z);
            acc[6] += ubf_lo(vc.w); acc[7] += ubf_hi(vc.w);
            acc[0] += ubf_lo(vd.x); acc[1] += ubf_hi(vd.x);
            acc[2] += ubf_lo(vd.y); acc[3] += ubf_hi(vd.y);
            acc[4] += ubf_lo(vd.z); acc[5] += ubf_hi(vd.z);
            acc[6] += ubf_lo(vd.w); acc[7] += ubf_hi(vd.w);
        }
        for (; i < end; ++i) {
            int sa = csr[i];
            uint4 va = *(const uint4*)(Gb + ((long)sa << 6) + fo);
            acc[0] += ubf_lo(va.x); acc[1] += ubf_hi(va.x);
            acc[2] += ubf_lo(va.y); acc[3] += ubf_hi(va.y);
            acc[4] += ubf_lo(va.z); acc[5] += ubf_hi(va.z);
            acc[6] += ubf_lo(va.w); acc[7] += ubf_hi(va.w);
        }
        *(float4*)&sz[nl][fo]     = make_float4(acc[0], acc[1], acc[2], acc[3]);
        *(float4*)&sz[nl][fo + 4] = make_float4(acc[4], acc[5], acc[6], acc[7]);
    }
    __syncthreads();

    const int cg = tid & 15;
    const int ng = tid >> 4;
    float acc[2][4];

    // ---- layer 1 (read sz) ----
    #pragma unroll
    for (int ni = 0; ni < 2; ++ni)
        #pragma unroll
        for (int ci = 0; ci < 4; ++ci) acc[ni][ci] = sb1[cg * 4 + ci];

    #pragma unroll 4
    for (int k = 0; k < D; ++k) {
        float4 wv = *(const float4*)&sw1[k][cg * 4];
        #pragma unroll
        for (int ni = 0; ni < 2; ++ni) {
            float zv = sz[ng * 2 + ni][k];
            acc[ni][0] += zv * wv.x;
            acc[ni][1] += zv * wv.y;
            acc[ni][2] += zv * wv.z;
            acc[ni][3] += zv * wv.w;
        }
    }
    // hold relu(y) in registers, then overwrite sz after all reads complete
    float y[2][4];
    #pragma unroll
    for (int ni = 0; ni < 2; ++ni)
        #pragma unroll
        for (int ci = 0; ci < 4; ++ci)
            y[ni][ci] = acc[ni][ci] > 0.f ? acc[ni][ci] : 0.f;
    __syncthreads();
    #pragma unroll
    for (int ni = 0; ni < 2; ++ni)
        *(float4*)&sz[ng * 2 + ni][cg * 4] =
            make_float4(y[ni][0], y[ni][1], y[ni][2], y[ni][3]);
    __syncthreads();

    // ---- layer 2 (read sz = layer-1 output) ----
    #pragma unroll
    for (int ni = 0; ni < 2; ++ni)
        #pragma unroll
        for (int ci = 0; ci < 4; ++ci) acc[ni][ci] = sb2[cg * 4 + ci];

    #pragma unroll 4
    for (int k = 0; k < D; ++k) {
        float4 wv = *(const float4*)&sw2[k][cg * 4];
        #pragma unroll
        for (int ni = 0; ni < 2; ++ni) {
            float yv = sz[ng * 2 + ni][k];
            acc[ni][0] += yv * wv.x;
            acc[ni][1] += yv * wv.y;
            acc[ni][2] += yv * wv.z;
            acc[ni][3] += yv * wv.w;
        }
    }
    #pragma unroll
    for (int ni = 0; ni < 2; ++ni) {
        float4 o;
        o.x = acc[ni][0]; o.y = acc[ni][1]; o.z = acc[ni][2]; o.w = acc[ni][3];
        if (FINAL_RELU) {
            o.x = o.x > 0.f ? o.x : 0.f;
            o.y = o.y > 0.f ? o.y : 0.f;
            o.z = o.z > 0.f ? o.z : 0.f;
            o.w = o.w > 0.f ? o.w : 0.f;
        }
        long node = nbase + ng * 2 + ni;
        *(float4*)(OutF + node * D + cg * 4) = o;
        if (WRITE_BF16) {
            uint2 p;
            p.x = bf1(o.x) | (bf1(o.y) << 16);
            p.y = bf1(o.z) | (bf1(o.w) << 16);
            *(uint2*)(OutB + node * D + cg * 4) = p;
        }
    }
}

// ================= pooling =================
__device__ inline void atomicMaxFloat(float* addr, float val) {
    if (val >= 0.f) atomicMax((int*)addr, __float_as_int(val));
    else            atomicMin((unsigned int*)addr, __float_as_uint(val));
}

__global__ __launch_bounds__(256) void k_pool(const float* __restrict__ H,
                                              const int* __restrict__ batch,
                                              float* __restrict__ psum,
                                              float* __restrict__ pmax) {
    long gt = (long)blockIdx.x * blockDim.x + threadIdx.x;
    int wave = (int)(gt >> 6);
    int lane = (int)(gt & 63);
    int n0 = wave * 16;
    if (n0 >= N_NODES) return;
    int curg = batch[n0];
    float accs = 0.f;
    float accm = -INFINITY;
    #pragma unroll 4
    for (int i = 0; i < 16; ++i) {
        int n = n0 + i;
        if (n >= N_NODES) break;
        int g = batch[n];
        if (g != curg) {
            atomicAdd(&psum[curg * D + lane], accs);
            atomicMaxFloat(&pmax[curg * D + lane], accm);
            accs = 0.f; accm = -INFINITY; curg = g;
        }
        float v = H[(long)n * D + lane];
        accs += v;
        accm = accm > v ? accm : v;
    }
    atomicAdd(&psum[curg * D + lane], accs);
    atomicMaxFloat(&pmax[curg * D + lane], accm);
}

// ================= MLP head =================
__device__ inline float silu(float x) { return x / (1.f + expf(-x)); }

__global__ __launch_bounds__(128) void k_head(
    const float* __restrict__ psum, const float* __restrict__ pmax,
    const float* __restrict__ w0, const float* __restrict__ b0,
    const float* __restrict__ w1, const float* __restrict__ b1,
    const float* __restrict__ w2, const float* __restrict__ b2,
    const float* __restrict__ w3, const float* __restrict__ b3,
    const float* __restrict__ w4, const float* __restrict__ b4,
    float* __restrict__ out)
{
    __shared__ float bufA[128];
    __shared__ float bufB[128];
    int g = blockIdx.x, t = threadIdx.x;
    bufA[t] = (t < 64) ? psum[g * 64 + t] : pmax[g * 64 + (t - 64)];
    __syncthreads();
    {
        float a = b0[t];
        for (int k = 0; k < 128; ++k) a += bufA[k] * w0[k * 128 + t];
        bufB[t] = silu(a);
    }
    __syncthreads();
    if (t < 64) {
        float a = b1[t];
        for (int k = 0; k < 128; ++k) a += bufB[k] * w1[k * 64 + t];
        bufA[t] = silu(a);
    }
    __syncthreads();
    if (t < 32) {
        float a = b2[t];
        for (int k = 0; k < 64; ++k) a += bufA[k] * w2[k * 32 + t];
        bufB[t] = silu(a);
    }
    __syncthreads();
    if (t < 16) {
        float a = b3[t];
        for (int k = 0; k < 32; ++k) a += bufB[k] * w3[k * 16 + t];
        bufA[t] = silu(a);
    }
    __syncthreads();
    if (t == 0) {
        float a = b4[0];
        for (int k = 0; k < 16; ++k) a += bufA[k] * w4[k];
        out[g] = a;
    }
}

extern "C" void kernel_launch(void* const* d_in, const int* in_sizes, int n_in,
                              void* d_out, int out_size, void* d_ws, size_t ws_size,
                              hipStream_t stream) {
    const float* x     = (const float*)d_in[0];
    const int*   ei    = (const int*)d_in[1];
    const int*   batch = (const int*)d_in[2];
    const float* c1w1 = (const float*)d_in[3];
    const float* c1b1 = (const float*)d_in[4];
    const float* c1w2 = (const float*)d_in[5];
    const float* c1b2 = (const float*)d_in[6];
    const float* c2w1 = (const float*)d_in[7];
    const float* c2b1 = (const float*)d_in[8];
    const float* c2w2 = (const float*)d_in[9];
    const float* c2b2 = (const float*)d_in[10];
    const float* hw0 = (const float*)d_in[11];
    const float* hb0 = (const float*)d_in[12];
    const float* hw1 = (const float*)d_in[13];
    const float* hb1 = (const float*)d_in[14];
    const float* hw2 = (const float*)d_in[15];
    const float* hb2 = (const float*)d_in[16];
    const float* hw3 = (const float*)d_in[17];
    const float* hb3 = (const float*)d_in[18];
    const float* hw4 = (const float*)d_in[19];
    const float* hb4 = (const float*)d_in[20];

    const size_t NF = (size_t)N_NODES * D;
    float*  H    = (float*)d_ws;                        // 51.2 MB
    ushort* xb   = (ushort*)(H + NF);                   // 25.6 MB
    ushort* hb   = xb + NF;                             // 25.6 MB
    float*  psum = (float*)(hb + NF);
    float*  pmax = psum + NGRAPH * D;
    int* rowptr  = (int*)(pmax + NGRAPH * D);           // N_NODES+4
    int* gcur    = rowptr + (N_NODES + 4);              // 256 (zeroed with rowptr)
    int* cursor  = gcur + 256;                          // N_NODES
    int* blksum  = cursor + N_NODES;                    // 256
    int* csr     = blksum + 256;                        // N_EDGES
    uint* recs   = (uint*)(csr + N_EDGES);              // BKT*BCAP
    float* out   = (float*)d_out;

    const int* srcs = ei;
    const int* dsts = ei + N_EDGES;

    const int edgeBlocks = (N_EDGES + 255) / 256;       // 4883
    const int scanBlocks = (N_NODES + 1023) / 1024;     // 196
    const int partBlocks = (N_EDGES + 4095) / 4096;     // 306
    const int convBlocks = N_NODES / 64;                // 3125
    const int castBlocks = (int)(NF / (256 * 8));       // 6250
    const int initBlocks = (NGRAPH * D + 255) / 256;    // 32
    const int poolBlocks = N_NODES / 64;                // 3125

    // ---- CSR build (by dst) ----
    hipMemsetAsync(rowptr, 0, (N_NODES + 4 + 256) * sizeof(int), stream);
    k_hist <<<edgeBlocks, 256, 0, stream>>>(dsts, rowptr);
    k_scan1<<<scanBlocks, 256, 0, stream>>>(rowptr, blksum, N_NODES);
    k_scan2<<<1,          256, 0, stream>>>(blksum, scanBlocks);
    k_scan3<<<scanBlocks, 256, 0, stream>>>(rowptr, blksum, cursor, N_NODES);
    k_part <<<partBlocks, 256, 0, stream>>>(srcs, dsts, gcur, recs);
    k_fill2<<<BKT * 2,    256, 0, stream>>>(recs, gcur, cursor, csr);

    // ---- bf16 copy of x + pool-buffer init ----
    k_cast<<<castBlocks + initBlocks, 256, 0, stream>>>(x, xb, psum, pmax, castBlocks);

    // ---- conv1 ----
    k_gin_fused<1, 1><<<convBlocks, 512, 0, stream>>>(
        x, xb, rowptr, csr, c1w1, c1b1, c1w2, c1b2, H, hb);

    // ---- conv2 (in place) ----
    k_gin_fused<0, 0><<<convBlocks, 512, 0, stream>>>(
        H, hb, rowptr, csr, c2w1, c2b1, c2w2, c2b2, H, (ushort*)nullptr);

    // ---- pooling ----
    k_pool<<<poolBlocks, 256, 0, stream>>>(H, batch, psum, pmax);

    // ---- head ----
    k_head<<<NGRAPH, 128, 0, stream>>>(psum, pmax,
                                       hw0, hb0, hw1, hb1, hw2, hb2, hw3, hb3, hw4, hb4,
                                       out);
}

// Round 6
// 187.025 us; speedup vs baseline: 3.8230x; 1.7227x over previous
//
#include <hip/hip_runtime.h>
#include <math.h>

#define N_NODES  200000
#define N_EDGES  1250000
#define D        64
#define NGRAPH   128

#define BKT   196     // dst buckets: dst>>10
#define BSH   10
#define BCAP  8192    // capacity per bucket (mean 6400)

#define PARTB 306     // (N_EDGES+4095)/4096
#define CASTB 6250    // N_NODES*D/(256*8)
#define INITB 32      // (NGRAPH*D+255)/256

typedef unsigned int uint;
typedef unsigned short ushort;
typedef __attribute__((ext_vector_type(8))) short frag;     // 8 bf16
typedef __attribute__((ext_vector_type(4))) float f32x4;

__device__ inline uint bf1(float a) {
    uint u = __float_as_uint(a);
    return (u + 0x7fffu + ((u >> 16) & 1u)) >> 16;
}
__device__ inline float ubf_lo(uint u) { return __uint_as_float(u << 16); }
__device__ inline float ubf_hi(uint u) { return __uint_as_float(u & 0xffff0000u); }

// ========== fused: edge partition (records per dst-bucket) + x->bf16 cast + pool init ==========
__global__ __launch_bounds__(256) void k_part_cast(
    const int* __restrict__ srcs, const int* __restrict__ dsts,
    int* __restrict__ gcur, uint* __restrict__ recs,
    const float* __restrict__ x, ushort* __restrict__ xb,
    float* __restrict__ psum, float* __restrict__ pmax)
{
    const int bid = blockIdx.x;
    const int tid = threadIdx.x;
    if (bid < PARTB) {
        __shared__ int lhist[BKT];
        __shared__ int lbase[BKT];
        const long ebase = (long)bid * 4096;
        for (int i = tid; i < BKT; i += 256) lhist[i] = 0;
        __syncthreads();
        #pragma unroll
        for (int j = 0; j < 16; ++j) {
            long e = ebase + j * 256 + tid;
            if (e < N_EDGES) atomicAdd(&lhist[dsts[e] >> BSH], 1);
        }
        __syncthreads();
        for (int i = tid; i < BKT; i += 256) {
            int c = lhist[i];
            lbase[i] = c > 0 ? atomicAdd(&gcur[i], c) : 0;
            lhist[i] = 0;
        }
        __syncthreads();
        #pragma unroll
        for (int j = 0; j < 16; ++j) {
            long e = ebase + j * 256 + tid;
            if (e < N_EDGES) {
                int d = dsts[e];
                int s = srcs[e];
                int b = d >> BSH;
                int r = atomicAdd(&lhist[b], 1);
                recs[(long)b * BCAP + lbase[b] + r] = ((uint)(d & 1023) << 18) | (uint)s;
            }
        }
    } else if (bid < PARTB + CASTB) {
        long base = ((long)(bid - PARTB) * 256 + tid) * 8;
        float4 a = *(const float4*)(x + base);
        float4 b = *(const float4*)(x + base + 4);
        uint4 o;
        o.x = bf1(a.x) | (bf1(a.y) << 16);
        o.y = bf1(a.z) | (bf1(a.w) << 16);
        o.z = bf1(b.x) | (bf1(b.y) << 16);
        o.w = bf1(b.z) | (bf1(b.w) << 16);
        *(uint4*)(xb + base) = o;
    } else {
        int t = (bid - PARTB - CASTB) * 256 + tid;
        if (t < NGRAPH * D) {
            psum[t] = 0.f;
            pmax[t] = -INFINITY;
        }
    }
}

// ========== per-bucket CSR build: degree hist + scan + scatter, all block-local ==========
__global__ __launch_bounds__(512) void k_fill2(const uint* __restrict__ recs,
                                               const int* __restrict__ gcur,
                                               int* __restrict__ csr,
                                               int* __restrict__ rowbeg,
                                               int* __restrict__ rowend)
{
    __shared__ uint srec[BCAP];   // 32 KB record stage
    __shared__ int  sdeg[1024];
    __shared__ int  soff[1024];
    __shared__ int  ss[512];
    const int b = blockIdx.x;
    const int tid = threadIdx.x;
    int cnt = gcur[b];
    if (cnt > BCAP) cnt = BCAP;
    for (int i = tid; i < 1024; i += 512) sdeg[i] = 0;
    __syncthreads();
    for (int i = tid; i < cnt; i += 512) {
        uint r = recs[(long)b * BCAP + i];
        srec[i] = r;
        atomicAdd(&sdeg[r >> 18], 1);
    }
    __syncthreads();
    // exclusive scan over 1024 degrees (each thread owns 2)
    int v0 = sdeg[2 * tid];
    int v1 = sdeg[2 * tid + 1];
    int ts = v0 + v1;
    ss[tid] = ts;
    __syncthreads();
    for (int off = 1; off < 512; off <<= 1) {
        int t = (tid >= off) ? ss[tid - off] : 0;
        __syncthreads();
        ss[tid] += t;
        __syncthreads();
    }
    int ex = ss[tid] - ts;
    soff[2 * tid]     = ex;
    soff[2 * tid + 1] = ex + v0;
    // row ranges (global csr indices, bucket-strided layout)
    const int dbase = b << BSH;
    const int gbase = b * BCAP;
    int n0 = dbase + 2 * tid;
    if (n0 < N_NODES)     { rowbeg[n0] = gbase + ex;      rowend[n0] = gbase + ex + v0; }
    if (n0 + 1 < N_NODES) { rowbeg[n0+1] = gbase + ex + v0; rowend[n0+1] = gbase + ex + v0 + v1; }
    __syncthreads();
    // scatter records into csr via LDS cursors
    for (int i = tid; i < cnt; i += 512) {
        uint r = srec[i];
        int pos = atomicAdd(&soff[r >> 18], 1);
        csr[gbase + pos] = (int)(r & 0x3FFFFu);
    }
}

// ========== fused GIN conv: bf16 gather + MFMA 2-layer MLP ==========
// z = Self(fp32) + sum_nbr Gb(bf16); Out = [relu](relu(z@w1+b1)@w2+b2)
template<int FINAL_RELU, int WRITE_BF16>
__global__ __launch_bounds__(512) void k_conv(
    const float* __restrict__ Self, const ushort* __restrict__ Gb,
    const int* __restrict__ rowbeg, const int* __restrict__ rowend,
    const int* __restrict__ csr,
    const float* __restrict__ w1g, const float* __restrict__ b1g,
    const float* __restrict__ w2g, const float* __restrict__ b2g,
    float* __restrict__ OutF, ushort* __restrict__ OutB)
{
    __shared__ ushort z_s[64 * 72];    // z (then y) as bf16, row stride 72
    __shared__ ushort wt1[64 * 72];    // w1 transposed: wt1[c][k]
    __shared__ ushort wt2[64 * 72];
    __shared__ float sb1[64], sb2[64];
    const int tid = threadIdx.x;
    const long nbase = (long)blockIdx.x * 64;

    // ---- stage transposed bf16 weights: thread t -> col c, k-octet kq ----
    {
        const int c = tid & 63;
        const int k0 = (tid >> 6) * 8;
        float v[8], w[8];
        #pragma unroll
        for (int j = 0; j < 8; ++j) {
            v[j] = w1g[(k0 + j) * D + c];
            w[j] = w2g[(k0 + j) * D + c];
        }
        uint4 p1, p2;
        p1.x = bf1(v[0]) | (bf1(v[1]) << 16);
        p1.y = bf1(v[2]) | (bf1(v[3]) << 16);
        p1.z = bf1(v[4]) | (bf1(v[5]) << 16);
        p1.w = bf1(v[6]) | (bf1(v[7]) << 16);
        p2.x = bf1(w[0]) | (bf1(w[1]) << 16);
        p2.y = bf1(w[2]) | (bf1(w[3]) << 16);
        p2.z = bf1(w[4]) | (bf1(w[5]) << 16);
        p2.w = bf1(w[6]) | (bf1(w[7]) << 16);
        *(uint4*)&wt1[c * 72 + k0] = p1;
        *(uint4*)&wt2[c * 72 + k0] = p2;
        if (tid < 64) sb1[tid] = b1g[tid];
        else if (tid < 128) sb2[tid - 64] = b2g[tid - 64];
    }

    // ---- gather: 8 threads/node, 8 feats each; z -> bf16 LDS ----
    {
        const int nl = tid >> 3;
        const int fo = (tid & 7) * 8;
        const long n = nbase + nl;
        float acc[8];
        float4 s0 = *(const float4*)(Self + n * D + fo);
        float4 s1 = *(const float4*)(Self + n * D + fo + 4);
        acc[0] = s0.x; acc[1] = s0.y; acc[2] = s0.z; acc[3] = s0.w;
        acc[4] = s1.x; acc[5] = s1.y; acc[6] = s1.z; acc[7] = s1.w;
        int i = rowbeg[n];
        const int end = rowend[n];
        for (; i + 3 < end; i += 4) {
            int sa = csr[i];
            int sb = csr[i + 1];
            int sc = csr[i + 2];
            int sd = csr[i + 3];
            uint4 va = *(const uint4*)(Gb + ((long)sa << 6) + fo);
            uint4 vb = *(const uint4*)(Gb + ((long)sb << 6) + fo);
            uint4 vc = *(const uint4*)(Gb + ((long)sc << 6) + fo);
            uint4 vd = *(const uint4*)(Gb + ((long)sd << 6) + fo);
            acc[0] += ubf_lo(va.x); acc[1] += ubf_hi(va.x);
            acc[2] += ubf_lo(va.y); acc[3] += ubf_hi(va.y);
            acc[4] += ubf_lo(va.z); acc[5] += ubf_hi(va.z);
            acc[6] += ubf_lo(va.w); acc[7] += ubf_hi(va.w);
            acc[0] += ubf_lo(vb.x); acc[1] += ubf_hi(vb.x);
            acc[2] += ubf_lo(vb.y); acc[3] += ubf_hi(vb.y);
            acc[4] += ubf_lo(vb.z); acc[5] += ubf_hi(vb.z);
            acc[6] += ubf_lo(vb.w); acc[7] += ubf_hi(vb.w);
            acc[0] += ubf_lo(vc.x); acc[1] += ubf_hi(vc.x);
            acc[2] += ubf_lo(vc.y); acc[3] += ubf_hi(vc.y);
            acc[4] += ubf_lo(vc.z); acc[5] += ubf_hi(vc.z);
            acc[6] += ubf_lo(vc.w); acc[7] += ubf_hi(vc.w);
            acc[0] += ubf_lo(vd.x); acc[1] += ubf_hi(vd.x);
            acc[2] += ubf_lo(vd.y); acc[3] += ubf_hi(vd.y);
            acc[4] += ubf_lo(vd.z); acc[5] += ubf_hi(vd.z);
            acc[6] += ubf_lo(vd.w); acc[7] += ubf_hi(vd.w);
        }
        for (; i < end; ++i) {
            int sa = csr[i];
            uint4 va = *(const uint4*)(Gb + ((long)sa << 6) + fo);
            acc[0] += ubf_lo(va.x); acc[1] += ubf_hi(va.x);
            acc[2] += ubf_lo(va.y); acc[3] += ubf_hi(va.y);
            acc[4] += ubf_lo(va.z); acc[5] += ubf_hi(va.z);
            acc[6] += ubf_lo(va.w); acc[7] += ubf_hi(va.w);
        }
        uint4 o;
        o.x = bf1(acc[0]) | (bf1(acc[1]) << 16);
        o.y = bf1(acc[2]) | (bf1(acc[3]) << 16);
        o.z = bf1(acc[4]) | (bf1(acc[5]) << 16);
        o.w = bf1(acc[6]) | (bf1(acc[7]) << 16);
        *(uint4*)&z_s[nl * 72 + fo] = o;
    }
    __syncthreads();

    // ---- MFMA: 8 waves = 4 node-groups x 2 col-halves ----
    const int lane = tid & 63;
    const int wid = tid >> 6;
    const int rbase = (wid >> 1) * 16;
    const int cbase = (wid & 1) * 32;
    const int r16 = lane & 15;
    const int kg = lane >> 4;           // 0..3
    const int c0 = cbase + r16;
    const int c1 = cbase + 16 + r16;

    // layer 1
    frag a0 = *(const frag*)&z_s[(rbase + r16) * 72 + kg * 8];
    frag a1 = *(const frag*)&z_s[(rbase + r16) * 72 + 32 + kg * 8];
    frag b00 = *(const frag*)&wt1[c0 * 72 + kg * 8];
    frag b01 = *(const frag*)&wt1[c0 * 72 + 32 + kg * 8];
    frag b10 = *(const frag*)&wt1[c1 * 72 + kg * 8];
    frag b11 = *(const frag*)&wt1[c1 * 72 + 32 + kg * 8];
    f32x4 acc0, acc1;
    #pragma unroll
    for (int r = 0; r < 4; ++r) { acc0[r] = sb1[c0]; acc1[r] = sb1[c1]; }
    acc0 = __builtin_amdgcn_mfma_f32_16x16x32_bf16(a0, b00, acc0, 0, 0, 0);
    acc0 = __builtin_amdgcn_mfma_f32_16x16x32_bf16(a1, b01, acc0, 0, 0, 0);
    acc1 = __builtin_amdgcn_mfma_f32_16x16x32_bf16(a0, b10, acc1, 0, 0, 0);
    acc1 = __builtin_amdgcn_mfma_f32_16x16x32_bf16(a1, b11, acc1, 0, 0, 0);
    __syncthreads();   // all z reads complete before overwrite

    // y = relu(acc) -> bf16, back into z_s (D row = (lane>>4)*4 + reg)
    #pragma unroll
    for (int r = 0; r < 4; ++r) {
        int row = rbase + kg * 4 + r;
        float y0 = acc0[r] > 0.f ? acc0[r] : 0.f;
        float y1 = acc1[r] > 0.f ? acc1[r] : 0.f;
        z_s[row * 72 + c0] = (ushort)bf1(y0);
        z_s[row * 72 + c1] = (ushort)bf1(y1);
    }
    __syncthreads();

    // layer 2
    a0 = *(const frag*)&z_s[(rbase + r16) * 72 + kg * 8];
    a1 = *(const frag*)&z_s[(rbase + r16) * 72 + 32 + kg * 8];
    b00 = *(const frag*)&wt2[c0 * 72 + kg * 8];
    b01 = *(const frag*)&wt2[c0 * 72 + 32 + kg * 8];
    b10 = *(const frag*)&wt2[c1 * 72 + kg * 8];
    b11 = *(const frag*)&wt2[c1 * 72 + 32 + kg * 8];
    #pragma unroll
    for (int r = 0; r < 4; ++r) { acc0[r] = sb2[c0]; acc1[r] = sb2[c1]; }
    acc0 = __builtin_amdgcn_mfma_f32_16x16x32_bf16(a0, b00, acc0, 0, 0, 0);
    acc0 = __builtin_amdgcn_mfma_f32_16x16x32_bf16(a1, b01, acc0, 0, 0, 0);
    acc1 = __builtin_amdgcn_mfma_f32_16x16x32_bf16(a0, b10, acc1, 0, 0, 0);
    acc1 = __builtin_amdgcn_mfma_f32_16x16x32_bf16(a1, b11, acc1, 0, 0, 0);

    // epilogue
    #pragma unroll
    for (int r = 0; r < 4; ++r) {
        long node = nbase + rbase + kg * 4 + r;
        float v0 = acc0[r], v1 = acc1[r];
        if (FINAL_RELU) {
            v0 = v0 > 0.f ? v0 : 0.f;
            v1 = v1 > 0.f ? v1 : 0.f;
        }
        OutF[node * D + c0] = v0;
        OutF[node * D + c1] = v1;
        if (WRITE_BF16) {
            OutB[node * D + c0] = (ushort)bf1(v0);
            OutB[node * D + c1] = (ushort)bf1(v1);
        }
    }
}

// ================= pooling =================
__device__ inline void atomicMaxFloat(float* addr, float val) {
    if (val >= 0.f) atomicMax((int*)addr, __float_as_int(val));
    else            atomicMin((unsigned int*)addr, __float_as_uint(val));
}

__global__ __launch_bounds__(256) void k_pool(const float* __restrict__ H,
                                              const int* __restrict__ batch,
                                              float* __restrict__ psum,
                                              float* __restrict__ pmax) {
    long gt = (long)blockIdx.x * blockDim.x + threadIdx.x;
    int wave = (int)(gt >> 6);
    int lane = (int)(gt & 63);
    int n0 = wave * 16;
    if (n0 >= N_NODES) return;
    int curg = batch[n0];
    float accs = 0.f;
    float accm = -INFINITY;
    #pragma unroll 4
    for (int i = 0; i < 16; ++i) {
        int n = n0 + i;
        if (n >= N_NODES) break;
        int g = batch[n];
        if (g != curg) {
            atomicAdd(&psum[curg * D + lane], accs);
            atomicMaxFloat(&pmax[curg * D + lane], accm);
            accs = 0.f; accm = -INFINITY; curg = g;
        }
        float v = H[(long)n * D + lane];
        accs += v;
        accm = accm > v ? accm : v;
    }
    atomicAdd(&psum[curg * D + lane], accs);
    atomicMaxFloat(&pmax[curg * D + lane], accm);
}

// ================= MLP head =================
__device__ inline float silu(float x) { return x / (1.f + expf(-x)); }

__global__ __launch_bounds__(128) void k_head(
    const float* __restrict__ psum, const float* __restrict__ pmax,
    const float* __restrict__ w0, const float* __restrict__ b0,
    const float* __restrict__ w1, const float* __restrict__ b1,
    const float* __restrict__ w2, const float* __restrict__ b2,
    const float* __restrict__ w3, const float* __restrict__ b3,
    const float* __restrict__ w4, const float* __restrict__ b4,
    float* __restrict__ out)
{
    __shared__ float bufA[128];
    __shared__ float bufB[128];
    int g = blockIdx.x, t = threadIdx.x;
    bufA[t] = (t < 64) ? psum[g * 64 + t] : pmax[g * 64 + (t - 64)];
    __syncthreads();
    {
        float a = b0[t];
        for (int k = 0; k < 128; ++k) a += bufA[k] * w0[k * 128 + t];
        bufB[t] = silu(a);
    }
    __syncthreads();
    if (t < 64) {
        float a = b1[t];
        for (int k = 0; k < 128; ++k) a += bufB[k] * w1[k * 64 + t];
        bufA[t] = silu(a);
    }
    __syncthreads();
    if (t < 32) {
        float a = b2[t];
        for (int k = 0; k < 64; ++k) a += bufA[k] * w2[k * 32 + t];
        bufB[t] = silu(a);
    }
    __syncthreads();
    if (t < 16) {
        float a = b3[t];
        for (int k = 0; k < 32; ++k) a += bufB[k] * w3[k * 16 + t];
        bufA[t] = silu(a);
    }
    __syncthreads();
    if (t == 0) {
        float a = b4[0];
        for (int k = 0; k < 16; ++k) a += bufA[k] * w4[k];
        out[g] = a;
    }
}

extern "C" void kernel_launch(void* const* d_in, const int* in_sizes, int n_in,
                              void* d_out, int out_size, void* d_ws, size_t ws_size,
                              hipStream_t stream) {
    const float* x     = (const float*)d_in[0];
    const int*   ei    = (const int*)d_in[1];
    const int*   batch = (const int*)d_in[2];
    const float* c1w1 = (const float*)d_in[3];
    const float* c1b1 = (const float*)d_in[4];
    const float* c1w2 = (const float*)d_in[5];
    const float* c1b2 = (const float*)d_in[6];
    const float* c2w1 = (const float*)d_in[7];
    const float* c2b1 = (const float*)d_in[8];
    const float* c2w2 = (const float*)d_in[9];
    const float* c2b2 = (const float*)d_in[10];
    const float* hw0 = (const float*)d_in[11];
    const float* hb0 = (const float*)d_in[12];
    const float* hw1 = (const float*)d_in[13];
    const float* hb1 = (const float*)d_in[14];
    const float* hw2 = (const float*)d_in[15];
    const float* hb2 = (const float*)d_in[16];
    const float* hw3 = (const float*)d_in[17];
    const float* hb3 = (const float*)d_in[18];
    const float* hw4 = (const float*)d_in[19];
    const float* hb4 = (const float*)d_in[20];

    const size_t NF = (size_t)N_NODES * D;
    float*  H    = (float*)d_ws;                        // 51.2 MB
    ushort* xb   = (ushort*)(H + NF);                   // 25.6 MB
    ushort* hb   = xb + NF;                             // 25.6 MB
    float*  psum = (float*)(hb + NF);                   // 32 KB
    float*  pmax = psum + NGRAPH * D;                   // 32 KB
    int* gcur    = (int*)(pmax + NGRAPH * D);           // 256
    int* rowbeg  = gcur + 256;                          // 200000
    int* rowend  = rowbeg + N_NODES;                    // 200000
    int* csr     = rowend + N_NODES;                    // BKT*BCAP (6.4 MB)
    uint* recs   = (uint*)(csr + BKT * BCAP);           // BKT*BCAP (6.4 MB)
    float* out   = (float*)d_out;

    const int* srcs = ei;
    const int* dsts = ei + N_EDGES;

    const int convBlocks = N_NODES / 64;                // 3125
    const int poolBlocks = N_NODES / 64;                // 3125

    // 1. zero bucket counters
    hipMemsetAsync(gcur, 0, 256 * sizeof(int), stream);

    // 2. partition edges + bf16 cast of x + pool init (one fused dispatch)
    k_part_cast<<<PARTB + CASTB + INITB, 256, 0, stream>>>(
        srcs, dsts, gcur, recs, x, xb, psum, pmax);

    // 3. bucket-local CSR build (degrees, scan, scatter — no global scans)
    k_fill2<<<BKT, 512, 0, stream>>>(recs, gcur, csr, rowbeg, rowend);

    // 4. conv1: self=x(fp32), gather=xb(bf16) -> H(fp32) + hb(bf16)
    k_conv<1, 1><<<convBlocks, 512, 0, stream>>>(
        x, xb, rowbeg, rowend, csr, c1w1, c1b1, c1w2, c1b2, H, hb);

    // 5. conv2: self=H, gather=hb -> H in place
    k_conv<0, 0><<<convBlocks, 512, 0, stream>>>(
        H, hb, rowbeg, rowend, csr, c2w1, c2b1, c2w2, c2b2, H, (ushort*)nullptr);

    // 6. pooling
    k_pool<<<poolBlocks, 256, 0, stream>>>(H, batch, psum, pmax);

    // 7. head
    k_head<<<NGRAPH, 128, 0, stream>>>(psum, pmax,
                                       hw0, hb0, hw1, hb1, hw2, hb2, hw3, hb3, hw4, hb4,
                                       out);
}

// Round 7
// 138.397 us; speedup vs baseline: 5.1662x; 1.3514x over previous
//
#include <hip/hip_runtime.h>
#include <math.h>

#define N_NODES  200000
#define N_EDGES  1250000
#define D        64
#define NGRAPH   128

#define BKT   196     // dst buckets: dst>>10
#define BSH   10
#define BCAP  8192    // capacity per bucket (mean 6400)

#define PARTB 306     // (N_EDGES+4095)/4096
#define CASTB 6250    // N_NODES*D/(256*8)
#define INITB 32      // (NGRAPH*D+255)/256

typedef unsigned int uint;
typedef unsigned short ushort;
typedef __attribute__((ext_vector_type(8))) short frag;     // 8 bf16
typedef __attribute__((ext_vector_type(4))) float f32x4;

__device__ inline uint bf1(float a) {
    uint u = __float_as_uint(a);
    return (u + 0x7fffu + ((u >> 16) & 1u)) >> 16;
}
__device__ inline float ubf_lo(uint u) { return __uint_as_float(u << 16); }
__device__ inline float ubf_hi(uint u) { return __uint_as_float(u & 0xffff0000u); }

__device__ inline void atomicMaxFloat(float* addr, float val) {
    if (val >= 0.f) atomicMax((int*)addr, __float_as_int(val));
    else            atomicMin((unsigned int*)addr, __float_as_uint(val));
}

// ========== fused: edge partition + x->bf16 cast + pool init ==========
__global__ __launch_bounds__(256) void k_part_cast(
    const int* __restrict__ srcs, const int* __restrict__ dsts,
    int* __restrict__ gcur, uint* __restrict__ recs,
    const float* __restrict__ x, ushort* __restrict__ xb,
    float* __restrict__ psum, float* __restrict__ pmax)
{
    const int bid = blockIdx.x;
    const int tid = threadIdx.x;
    if (bid < PARTB) {
        __shared__ int lhist[BKT];
        __shared__ int lbase[BKT];
        const long ebase = (long)bid * 4096;
        for (int i = tid; i < BKT; i += 256) lhist[i] = 0;
        __syncthreads();
        #pragma unroll
        for (int j = 0; j < 16; ++j) {
            long e = ebase + j * 256 + tid;
            if (e < N_EDGES) atomicAdd(&lhist[dsts[e] >> BSH], 1);
        }
        __syncthreads();
        for (int i = tid; i < BKT; i += 256) {
            int c = lhist[i];
            lbase[i] = c > 0 ? atomicAdd(&gcur[i], c) : 0;
            lhist[i] = 0;
        }
        __syncthreads();
        #pragma unroll
        for (int j = 0; j < 16; ++j) {
            long e = ebase + j * 256 + tid;
            if (e < N_EDGES) {
                int d = dsts[e];
                int s = srcs[e];
                int b = d >> BSH;
                int r = atomicAdd(&lhist[b], 1);
                recs[(long)b * BCAP + lbase[b] + r] = ((uint)(d & 1023) << 18) | (uint)s;
            }
        }
    } else if (bid < PARTB + CASTB) {
        long base = ((long)(bid - PARTB) * 256 + tid) * 8;
        float4 a = *(const float4*)(x + base);
        float4 b = *(const float4*)(x + base + 4);
        uint4 o;
        o.x = bf1(a.x) | (bf1(a.y) << 16);
        o.y = bf1(a.z) | (bf1(a.w) << 16);
        o.z = bf1(b.x) | (bf1(b.y) << 16);
        o.w = bf1(b.z) | (bf1(b.w) << 16);
        *(uint4*)(xb + base) = o;
    } else {
        int t = (bid - PARTB - CASTB) * 256 + tid;
        if (t < NGRAPH * D) {
            psum[t] = 0.f;
            pmax[t] = -INFINITY;
        }
    }
}

// ========== per-bucket CSR build ==========
__global__ __launch_bounds__(512) void k_fill2(const uint* __restrict__ recs,
                                               const int* __restrict__ gcur,
                                               int* __restrict__ csr,
                                               int* __restrict__ rowbeg,
                                               int* __restrict__ rowend)
{
    __shared__ uint srec[BCAP];
    __shared__ int  sdeg[1024];
    __shared__ int  soff[1024];
    __shared__ int  ss[512];
    const int b = blockIdx.x;
    const int tid = threadIdx.x;
    int cnt = gcur[b];
    if (cnt > BCAP) cnt = BCAP;
    for (int i = tid; i < 1024; i += 512) sdeg[i] = 0;
    __syncthreads();
    for (int i = tid; i < cnt; i += 512) {
        uint r = recs[(long)b * BCAP + i];
        srec[i] = r;
        atomicAdd(&sdeg[r >> 18], 1);
    }
    __syncthreads();
    int v0 = sdeg[2 * tid];
    int v1 = sdeg[2 * tid + 1];
    int ts = v0 + v1;
    ss[tid] = ts;
    __syncthreads();
    for (int off = 1; off < 512; off <<= 1) {
        int t = (tid >= off) ? ss[tid - off] : 0;
        __syncthreads();
        ss[tid] += t;
        __syncthreads();
    }
    int ex = ss[tid] - ts;
    soff[2 * tid]     = ex;
    soff[2 * tid + 1] = ex + v0;
    const int dbase = b << BSH;
    const int gbase = b * BCAP;
    int n0 = dbase + 2 * tid;
    if (n0 < N_NODES)     { rowbeg[n0] = gbase + ex;        rowend[n0] = gbase + ex + v0; }
    if (n0 + 1 < N_NODES) { rowbeg[n0+1] = gbase + ex + v0; rowend[n0+1] = gbase + ex + v0 + v1; }
    __syncthreads();
    for (int i = tid; i < cnt; i += 512) {
        uint r = srec[i];
        int pos = atomicAdd(&soff[r >> 18], 1);
        csr[gbase + pos] = (int)(r & 0x3FFFFu);
    }
}

// ========== fused GIN conv: bf16 self+gather + MFMA MLP ==========
// MODE 0 (conv1): out = bf16(relu(mlp(z)))  -> OutB
// MODE 1 (conv2): out = mlp(z) pooled (sum/max per graph) -> psum/pmax atomics
template<int MODE>
__global__ __launch_bounds__(512) void k_conv(
    const ushort* __restrict__ Gb,
    const int* __restrict__ rowbeg, const int* __restrict__ rowend,
    const int* __restrict__ csr,
    const float* __restrict__ w1g, const float* __restrict__ b1g,
    const float* __restrict__ w2g, const float* __restrict__ b2g,
    ushort* __restrict__ OutB,
    const int* __restrict__ batch,
    float* __restrict__ psum, float* __restrict__ pmax)
{
    __shared__ ushort z_s[64 * 72];      // z / y bf16, row stride 72
    __shared__ ushort w_s[2][64 * 72];   // transposed weights [c][k]; reused as fp32 pool buf
    __shared__ float sb[2][64];
    __shared__ int sgid[64];
    const int tid = threadIdx.x;
    const long nbase = (long)blockIdx.x * 64;

    // ---- stage transposed bf16 weights ----
    {
        const int c = tid & 63;
        const int k0 = (tid >> 6) * 8;
        float v[8], w[8];
        #pragma unroll
        for (int j = 0; j < 8; ++j) {
            v[j] = w1g[(k0 + j) * D + c];
            w[j] = w2g[(k0 + j) * D + c];
        }
        uint4 p1, p2;
        p1.x = bf1(v[0]) | (bf1(v[1]) << 16);
        p1.y = bf1(v[2]) | (bf1(v[3]) << 16);
        p1.z = bf1(v[4]) | (bf1(v[5]) << 16);
        p1.w = bf1(v[6]) | (bf1(v[7]) << 16);
        p2.x = bf1(w[0]) | (bf1(w[1]) << 16);
        p2.y = bf1(w[2]) | (bf1(w[3]) << 16);
        p2.z = bf1(w[4]) | (bf1(w[5]) << 16);
        p2.w = bf1(w[6]) | (bf1(w[7]) << 16);
        *(uint4*)&w_s[0][c * 72 + k0] = p1;
        *(uint4*)&w_s[1][c * 72 + k0] = p2;
        if (tid < 64) sb[0][tid] = b1g[tid];
        else if (tid < 128) sb[1][tid - 64] = b2g[tid - 64];
    }

    // ---- gather: 8 threads/node, 8 feats each; self also from bf16 array ----
    {
        const int nl = tid >> 3;
        const int fo = (tid & 7) * 8;
        const long n = nbase + nl;
        float acc[8];
        uint4 sv = *(const uint4*)(Gb + (n << 6) + fo);
        acc[0] = ubf_lo(sv.x); acc[1] = ubf_hi(sv.x);
        acc[2] = ubf_lo(sv.y); acc[3] = ubf_hi(sv.y);
        acc[4] = ubf_lo(sv.z); acc[5] = ubf_hi(sv.z);
        acc[6] = ubf_lo(sv.w); acc[7] = ubf_hi(sv.w);
        int i = rowbeg[n];
        const int end = rowend[n];
        for (; i + 3 < end; i += 4) {
            int sa = csr[i];
            int sb_ = csr[i + 1];
            int sc = csr[i + 2];
            int sd = csr[i + 3];
            uint4 va = *(const uint4*)(Gb + ((long)sa << 6) + fo);
            uint4 vb = *(const uint4*)(Gb + ((long)sb_ << 6) + fo);
            uint4 vc = *(const uint4*)(Gb + ((long)sc << 6) + fo);
            uint4 vd = *(const uint4*)(Gb + ((long)sd << 6) + fo);
            acc[0] += ubf_lo(va.x); acc[1] += ubf_hi(va.x);
            acc[2] += ubf_lo(va.y); acc[3] += ubf_hi(va.y);
            acc[4] += ubf_lo(va.z); acc[5] += ubf_hi(va.z);
            acc[6] += ubf_lo(va.w); acc[7] += ubf_hi(va.w);
            acc[0] += ubf_lo(vb.x); acc[1] += ubf_hi(vb.x);
            acc[2] += ubf_lo(vb.y); acc[3] += ubf_hi(vb.y);
            acc[4] += ubf_lo(vb.z); acc[5] += ubf_hi(vb.z);
            acc[6] += ubf_lo(vb.w); acc[7] += ubf_hi(vb.w);
            acc[0] += ubf_lo(vc.x); acc[1] += ubf_hi(vc.x);
            acc[2] += ubf_lo(vc.y); acc[3] += ubf_hi(vc.y);
            acc[4] += ubf_lo(vc.z); acc[5] += ubf_hi(vc.z);
            acc[6] += ubf_lo(vc.w); acc[7] += ubf_hi(vc.w);
            acc[0] += ubf_lo(vd.x); acc[1] += ubf_hi(vd.x);
            acc[2] += ubf_lo(vd.y); acc[3] += ubf_hi(vd.y);
            acc[4] += ubf_lo(vd.z); acc[5] += ubf_hi(vd.z);
            acc[6] += ubf_lo(vd.w); acc[7] += ubf_hi(vd.w);
        }
        for (; i < end; ++i) {
            int sa = csr[i];
            uint4 va = *(const uint4*)(Gb + ((long)sa << 6) + fo);
            acc[0] += ubf_lo(va.x); acc[1] += ubf_hi(va.x);
            acc[2] += ubf_lo(va.y); acc[3] += ubf_hi(va.y);
            acc[4] += ubf_lo(va.z); acc[5] += ubf_hi(va.z);
            acc[6] += ubf_lo(va.w); acc[7] += ubf_hi(va.w);
        }
        uint4 o;
        o.x = bf1(acc[0]) | (bf1(acc[1]) << 16);
        o.y = bf1(acc[2]) | (bf1(acc[3]) << 16);
        o.z = bf1(acc[4]) | (bf1(acc[5]) << 16);
        o.w = bf1(acc[6]) | (bf1(acc[7]) << 16);
        *(uint4*)&z_s[nl * 72 + fo] = o;
    }
    __syncthreads();

    // ---- MFMA: 8 waves = 4 node-groups x 2 col-halves ----
    const int lane = tid & 63;
    const int wid = tid >> 6;
    const int rbase = (wid >> 1) * 16;
    const int cbase = (wid & 1) * 32;
    const int r16 = lane & 15;
    const int kg = lane >> 4;
    const int c0 = cbase + r16;
    const int c1 = cbase + 16 + r16;

    // layer 1
    frag a0 = *(const frag*)&z_s[(rbase + r16) * 72 + kg * 8];
    frag a1 = *(const frag*)&z_s[(rbase + r16) * 72 + 32 + kg * 8];
    frag b00 = *(const frag*)&w_s[0][c0 * 72 + kg * 8];
    frag b01 = *(const frag*)&w_s[0][c0 * 72 + 32 + kg * 8];
    frag b10 = *(const frag*)&w_s[0][c1 * 72 + kg * 8];
    frag b11 = *(const frag*)&w_s[0][c1 * 72 + 32 + kg * 8];
    f32x4 acc0, acc1;
    #pragma unroll
    for (int r = 0; r < 4; ++r) { acc0[r] = sb[0][c0]; acc1[r] = sb[0][c1]; }
    acc0 = __builtin_amdgcn_mfma_f32_16x16x32_bf16(a0, b00, acc0, 0, 0, 0);
    acc0 = __builtin_amdgcn_mfma_f32_16x16x32_bf16(a1, b01, acc0, 0, 0, 0);
    acc1 = __builtin_amdgcn_mfma_f32_16x16x32_bf16(a0, b10, acc1, 0, 0, 0);
    acc1 = __builtin_amdgcn_mfma_f32_16x16x32_bf16(a1, b11, acc1, 0, 0, 0);
    __syncthreads();

    // y = relu -> bf16 back into z_s (C/D: row = kg*4 + r, col = r16-based)
    #pragma unroll
    for (int r = 0; r < 4; ++r) {
        int row = rbase + kg * 4 + r;
        float y0 = acc0[r] > 0.f ? acc0[r] : 0.f;
        float y1 = acc1[r] > 0.f ? acc1[r] : 0.f;
        z_s[row * 72 + c0] = (ushort)bf1(y0);
        z_s[row * 72 + c1] = (ushort)bf1(y1);
    }
    __syncthreads();

    // layer 2
    a0 = *(const frag*)&z_s[(rbase + r16) * 72 + kg * 8];
    a1 = *(const frag*)&z_s[(rbase + r16) * 72 + 32 + kg * 8];
    b00 = *(const frag*)&w_s[1][c0 * 72 + kg * 8];
    b01 = *(const frag*)&w_s[1][c0 * 72 + 32 + kg * 8];
    b10 = *(const frag*)&w_s[1][c1 * 72 + kg * 8];
    b11 = *(const frag*)&w_s[1][c1 * 72 + 32 + kg * 8];
    #pragma unroll
    for (int r = 0; r < 4; ++r) { acc0[r] = sb[1][c0]; acc1[r] = sb[1][c1]; }
    acc0 = __builtin_amdgcn_mfma_f32_16x16x32_bf16(a0, b00, acc0, 0, 0, 0);
    acc0 = __builtin_amdgcn_mfma_f32_16x16x32_bf16(a1, b01, acc0, 0, 0, 0);
    acc1 = __builtin_amdgcn_mfma_f32_16x16x32_bf16(a0, b10, acc1, 0, 0, 0);
    acc1 = __builtin_amdgcn_mfma_f32_16x16x32_bf16(a1, b11, acc1, 0, 0, 0);

    if (MODE == 0) {
        // conv1 epilogue: relu -> bf16 hb
        #pragma unroll
        for (int r = 0; r < 4; ++r) {
            long node = nbase + rbase + kg * 4 + r;
            float v0 = acc0[r] > 0.f ? acc0[r] : 0.f;
            float v1 = acc1[r] > 0.f ? acc1[r] : 0.f;
            OutB[node * D + c0] = (ushort)bf1(v0);
            OutB[node * D + c1] = (ushort)bf1(v1);
        }
    } else {
        // conv2 epilogue: fused graph pooling (sum + max), fp32 accumulators
        __syncthreads();                       // all LDS frag reads done -> safe to alias
        float* pbuf = (float*)&w_s[0][0];      // [64][66] fp32
        #pragma unroll
        for (int r = 0; r < 4; ++r) {
            int row = rbase + kg * 4 + r;
            pbuf[row * 66 + c0] = acc0[r];
            pbuf[row * 66 + c1] = acc1[r];
        }
        if (tid < 64) sgid[tid] = batch[nbase + tid];
        __syncthreads();
        const int g0 = sgid[0], g1 = sgid[63];
        float* rsum = (float*)&z_s[0];         // [8][64]
        float* rmax = rsum + 512;
        const int col = tid & 63;
        const int ch = tid >> 6;
        for (int g = g0; ; ++g) {
            float s = 0.f, m = -INFINITY;
            #pragma unroll
            for (int r = 0; r < 8; ++r) {
                int row = ch * 8 + r;
                if (sgid[row] == g) {
                    float v = pbuf[row * 66 + col];
                    s += v;
                    m = m > v ? m : v;
                }
            }
            rsum[ch * 64 + col] = s;
            rmax[ch * 64 + col] = m;
            __syncthreads();
            if (tid < 64) {
                float S = 0.f, M = -INFINITY;
                #pragma unroll
                for (int c = 0; c < 8; ++c) {
                    S += rsum[c * 64 + tid];
                    float mm = rmax[c * 64 + tid];
                    M = M > mm ? M : mm;
                }
                atomicAdd(&psum[g * 64 + tid], S);
                atomicMaxFloat(&pmax[g * 64 + tid], M);
            }
            if (g == g1) break;
            __syncthreads();
        }
    }
}

// ================= MLP head =================
__device__ inline float silu(float x) { return x / (1.f + expf(-x)); }

__global__ __launch_bounds__(128) void k_head(
    const float* __restrict__ psum, const float* __restrict__ pmax,
    const float* __restrict__ w0, const float* __restrict__ b0,
    const float* __restrict__ w1, const float* __restrict__ b1,
    const float* __restrict__ w2, const float* __restrict__ b2,
    const float* __restrict__ w3, const float* __restrict__ b3,
    const float* __restrict__ w4, const float* __restrict__ b4,
    float* __restrict__ out)
{
    __shared__ float bufA[128];
    __shared__ float bufB[128];
    int g = blockIdx.x, t = threadIdx.x;
    bufA[t] = (t < 64) ? psum[g * 64 + t] : pmax[g * 64 + (t - 64)];
    __syncthreads();
    {
        float a = b0[t];
        for (int k = 0; k < 128; ++k) a += bufA[k] * w0[k * 128 + t];
        bufB[t] = silu(a);
    }
    __syncthreads();
    if (t < 64) {
        float a = b1[t];
        for (int k = 0; k < 128; ++k) a += bufB[k] * w1[k * 64 + t];
        bufA[t] = silu(a);
    }
    __syncthreads();
    if (t < 32) {
        float a = b2[t];
        for (int k = 0; k < 64; ++k) a += bufA[k] * w2[k * 32 + t];
        bufB[t] = silu(a);
    }
    __syncthreads();
    if (t < 16) {
        float a = b3[t];
        for (int k = 0; k < 32; ++k) a += bufB[k] * w3[k * 16 + t];
        bufA[t] = silu(a);
    }
    __syncthreads();
    if (t == 0) {
        float a = b4[0];
        for (int k = 0; k < 16; ++k) a += bufA[k] * w4[k];
        out[g] = a;
    }
}

extern "C" void kernel_launch(void* const* d_in, const int* in_sizes, int n_in,
                              void* d_out, int out_size, void* d_ws, size_t ws_size,
                              hipStream_t stream) {
    const float* x     = (const float*)d_in[0];
    const int*   ei    = (const int*)d_in[1];
    const int*   batch = (const int*)d_in[2];
    const float* c1w1 = (const float*)d_in[3];
    const float* c1b1 = (const float*)d_in[4];
    const float* c1w2 = (const float*)d_in[5];
    const float* c1b2 = (const float*)d_in[6];
    const float* c2w1 = (const float*)d_in[7];
    const float* c2b1 = (const float*)d_in[8];
    const float* c2w2 = (const float*)d_in[9];
    const float* c2b2 = (const float*)d_in[10];
    const float* hw0 = (const float*)d_in[11];
    const float* hb0 = (const float*)d_in[12];
    const float* hw1 = (const float*)d_in[13];
    const float* hb1 = (const float*)d_in[14];
    const float* hw2 = (const float*)d_in[15];
    const float* hb2 = (const float*)d_in[16];
    const float* hw3 = (const float*)d_in[17];
    const float* hb3 = (const float*)d_in[18];
    const float* hw4 = (const float*)d_in[19];
    const float* hb4 = (const float*)d_in[20];

    const size_t NF = (size_t)N_NODES * D;
    ushort* xb   = (ushort*)d_ws;                       // 25.6 MB
    ushort* hb   = xb + NF;                             // 25.6 MB
    float*  psum = (float*)(hb + NF);                   // 32 KB
    float*  pmax = psum + NGRAPH * D;                   // 32 KB
    int* gcur    = (int*)(pmax + NGRAPH * D);           // 256
    int* rowbeg  = gcur + 256;                          // 200000
    int* rowend  = rowbeg + N_NODES;                    // 200000
    int* csr     = rowend + N_NODES;                    // BKT*BCAP (6.4 MB)
    uint* recs   = (uint*)(csr + BKT * BCAP);           // BKT*BCAP (6.4 MB)
    float* out   = (float*)d_out;

    const int* srcs = ei;
    const int* dsts = ei + N_EDGES;

    const int convBlocks = N_NODES / 64;                // 3125

    // 1. zero bucket counters
    hipMemsetAsync(gcur, 0, 256 * sizeof(int), stream);

    // 2. partition edges + bf16 cast of x + pool init
    k_part_cast<<<PARTB + CASTB + INITB, 256, 0, stream>>>(
        srcs, dsts, gcur, recs, x, xb, psum, pmax);

    // 3. bucket-local CSR build
    k_fill2<<<BKT, 512, 0, stream>>>(recs, gcur, csr, rowbeg, rowend);

    // 4. conv1: self+gather from xb -> hb (bf16 only)
    k_conv<0><<<convBlocks, 512, 0, stream>>>(
        xb, rowbeg, rowend, csr, c1w1, c1b1, c1w2, c1b2,
        hb, (const int*)nullptr, (float*)nullptr, (float*)nullptr);

    // 5. conv2: self+gather from hb -> fused pooling into psum/pmax
    k_conv<1><<<convBlocks, 512, 0, stream>>>(
        hb, rowbeg, rowend, csr, c2w1, c2b1, c2w2, c2b2,
        (ushort*)nullptr, batch, psum, pmax);

    // 6. head
    k_head<<<NGRAPH, 128, 0, stream>>>(psum, pmax,
                                       hw0, hb0, hw1, hb1, hw2, hb2, hw3, hb3, hw4, hb4,
                                       out);
}

// Round 8
// 137.046 us; speedup vs baseline: 5.2172x; 1.0099x over previous
//
#include <hip/hip_runtime.h>
#include <math.h>

#define N_NODES  200000
#define N_EDGES  1250000
#define D        64
#define NGRAPH   128

#define BKT   196     // dst buckets: dst>>10
#define BSH   10
#define BCAP  8192    // capacity per bucket (mean 6400)

#define PARTB 306     // (N_EDGES+4095)/4096
#define CASTB 6250    // N_NODES*D/(256*8)
#define INITB 32      // (NGRAPH*D+255)/256

typedef unsigned int uint;
typedef unsigned short ushort;
typedef __attribute__((ext_vector_type(8))) short frag;     // 8 bf16
typedef __attribute__((ext_vector_type(4))) float f32x4;

__device__ inline uint bf1(float a) {
    uint u = __float_as_uint(a);
    return (u + 0x7fffu + ((u >> 16) & 1u)) >> 16;
}
__device__ inline float ubf_lo(uint u) { return __uint_as_float(u << 16); }
__device__ inline float ubf_hi(uint u) { return __uint_as_float(u & 0xffff0000u); }

__device__ inline void atomicMaxFloat(float* addr, float val) {
    if (val >= 0.f) atomicMax((int*)addr, __float_as_int(val));
    else            atomicMin((unsigned int*)addr, __float_as_uint(val));
}

#define ACC8(v)                                         \
    acc[0] += ubf_lo(v.x); acc[1] += ubf_hi(v.x);       \
    acc[2] += ubf_lo(v.y); acc[3] += ubf_hi(v.y);       \
    acc[4] += ubf_lo(v.z); acc[5] += ubf_hi(v.z);       \
    acc[6] += ubf_lo(v.w); acc[7] += ubf_hi(v.w);

// ========== fused: edge partition + x->bf16 cast + pool init ==========
__global__ __launch_bounds__(256) void k_part_cast(
    const int* __restrict__ srcs, const int* __restrict__ dsts,
    int* __restrict__ gcur, uint* __restrict__ recs,
    const float* __restrict__ x, ushort* __restrict__ xb,
    float* __restrict__ psum, float* __restrict__ pmax)
{
    const int bid = blockIdx.x;
    const int tid = threadIdx.x;
    if (bid < PARTB) {
        __shared__ int lhist[BKT];
        __shared__ int lbase[BKT];
        const long ebase = (long)bid * 4096;
        for (int i = tid; i < BKT; i += 256) lhist[i] = 0;
        __syncthreads();
        #pragma unroll
        for (int j = 0; j < 16; ++j) {
            long e = ebase + j * 256 + tid;
            if (e < N_EDGES) atomicAdd(&lhist[dsts[e] >> BSH], 1);
        }
        __syncthreads();
        for (int i = tid; i < BKT; i += 256) {
            int c = lhist[i];
            lbase[i] = c > 0 ? atomicAdd(&gcur[i], c) : 0;
            lhist[i] = 0;
        }
        __syncthreads();
        #pragma unroll
        for (int j = 0; j < 16; ++j) {
            long e = ebase + j * 256 + tid;
            if (e < N_EDGES) {
                int d = dsts[e];
                int s = srcs[e];
                int b = d >> BSH;
                int r = atomicAdd(&lhist[b], 1);
                recs[(long)b * BCAP + lbase[b] + r] = ((uint)(d & 1023) << 18) | (uint)s;
            }
        }
    } else if (bid < PARTB + CASTB) {
        long base = ((long)(bid - PARTB) * 256 + tid) * 8;
        float4 a = *(const float4*)(x + base);
        float4 b = *(const float4*)(x + base + 4);
        uint4 o;
        o.x = bf1(a.x) | (bf1(a.y) << 16);
        o.y = bf1(a.z) | (bf1(a.w) << 16);
        o.z = bf1(b.x) | (bf1(b.y) << 16);
        o.w = bf1(b.z) | (bf1(b.w) << 16);
        *(uint4*)(xb + base) = o;
    } else {
        int t = (bid - PARTB - CASTB) * 256 + tid;
        if (t < NGRAPH * D) {
            psum[t] = 0.f;
            pmax[t] = -INFINITY;
        }
    }
}

// ========== per-bucket CSR build ==========
__global__ __launch_bounds__(512) void k_fill2(const uint* __restrict__ recs,
                                               const int* __restrict__ gcur,
                                               int* __restrict__ csr,
                                               int2* __restrict__ rows)
{
    __shared__ uint srec[BCAP];
    __shared__ int  sdeg[1024];
    __shared__ int  soff[1024];
    __shared__ int  ss[512];
    const int b = blockIdx.x;
    const int tid = threadIdx.x;
    int cnt = gcur[b];
    if (cnt > BCAP) cnt = BCAP;
    for (int i = tid; i < 1024; i += 512) sdeg[i] = 0;
    __syncthreads();
    for (int i = tid; i < cnt; i += 512) {
        uint r = recs[(long)b * BCAP + i];
        srec[i] = r;
        atomicAdd(&sdeg[r >> 18], 1);
    }
    __syncthreads();
    int v0 = sdeg[2 * tid];
    int v1 = sdeg[2 * tid + 1];
    int ts = v0 + v1;
    ss[tid] = ts;
    __syncthreads();
    for (int off = 1; off < 512; off <<= 1) {
        int t = (tid >= off) ? ss[tid - off] : 0;
        __syncthreads();
        ss[tid] += t;
        __syncthreads();
    }
    int ex = ss[tid] - ts;
    soff[2 * tid]     = ex;
    soff[2 * tid + 1] = ex + v0;
    const int dbase = b << BSH;
    const int gbase = b * BCAP;
    int n0 = dbase + 2 * tid;
    if (n0 < N_NODES)     rows[n0]   = make_int2(gbase + ex,      gbase + ex + v0);
    if (n0 + 1 < N_NODES) rows[n0+1] = make_int2(gbase + ex + v0, gbase + ex + v0 + v1);
    __syncthreads();
    for (int i = tid; i < cnt; i += 512) {
        uint r = srec[i];
        int pos = atomicAdd(&soff[r >> 18], 1);
        csr[gbase + pos] = (int)(r & 0x3FFFFu);
    }
}

// ========== fused GIN conv: bf16 self+gather + MFMA MLP ==========
// MODE 0 (conv1): out = bf16(relu(mlp(z)))  -> OutB
// MODE 1 (conv2): out = mlp(z) pooled (sum/max per graph) -> psum/pmax atomics
template<int MODE>
__global__ __launch_bounds__(512, 8) void k_conv(
    const ushort* __restrict__ Gb,
    const int2* __restrict__ rows,
    const int* __restrict__ csr,
    const float* __restrict__ w1g, const float* __restrict__ b1g,
    const float* __restrict__ w2g, const float* __restrict__ b2g,
    ushort* __restrict__ OutB,
    const int* __restrict__ batch,
    float* __restrict__ psum, float* __restrict__ pmax)
{
    __shared__ ushort z_s[64 * 72];      // z / y bf16, row stride 72
    __shared__ ushort w_s[2][64 * 72];   // transposed weights [c][k]; reused as fp32 pool buf
    __shared__ float sb[2][64];
    __shared__ int sgid[64];
    const int tid = threadIdx.x;
    const long nbase = (long)blockIdx.x * 64;

    // ---- stage transposed bf16 weights ----
    {
        const int c = tid & 63;
        const int k0 = (tid >> 6) * 8;
        float v[8], w[8];
        #pragma unroll
        for (int j = 0; j < 8; ++j) {
            v[j] = w1g[(k0 + j) * D + c];
            w[j] = w2g[(k0 + j) * D + c];
        }
        uint4 p1, p2;
        p1.x = bf1(v[0]) | (bf1(v[1]) << 16);
        p1.y = bf1(v[2]) | (bf1(v[3]) << 16);
        p1.z = bf1(v[4]) | (bf1(v[5]) << 16);
        p1.w = bf1(v[6]) | (bf1(v[7]) << 16);
        p2.x = bf1(w[0]) | (bf1(w[1]) << 16);
        p2.y = bf1(w[2]) | (bf1(w[3]) << 16);
        p2.z = bf1(w[4]) | (bf1(w[5]) << 16);
        p2.w = bf1(w[6]) | (bf1(w[7]) << 16);
        *(uint4*)&w_s[0][c * 72 + k0] = p1;
        *(uint4*)&w_s[1][c * 72 + k0] = p2;
        if (tid < 64) sb[0][tid] = b1g[tid];
        else if (tid < 128) sb[1][tid - 64] = b2g[tid - 64];
    }

    // ---- gather: 8 threads/node, 8 feats each; 8-deep load unroll ----
    {
        const int nl = tid >> 3;
        const int fo = (tid & 7) * 8;
        const long n = nbase + nl;
        float acc[8];
        uint4 sv = *(const uint4*)(Gb + (n << 6) + fo);
        acc[0] = ubf_lo(sv.x); acc[1] = ubf_hi(sv.x);
        acc[2] = ubf_lo(sv.y); acc[3] = ubf_hi(sv.y);
        acc[4] = ubf_lo(sv.z); acc[5] = ubf_hi(sv.z);
        acc[6] = ubf_lo(sv.w); acc[7] = ubf_hi(sv.w);
        const int2 rw = rows[n];
        int i = rw.x;
        const int end = rw.y;
        for (; i + 7 < end; i += 8) {
            int s0 = csr[i],     s1 = csr[i + 1], s2 = csr[i + 2], s3 = csr[i + 3];
            int s4 = csr[i + 4], s5 = csr[i + 5], s6 = csr[i + 6], s7 = csr[i + 7];
            uint4 v0 = *(const uint4*)(Gb + ((long)s0 << 6) + fo);
            uint4 v1 = *(const uint4*)(Gb + ((long)s1 << 6) + fo);
            uint4 v2 = *(const uint4*)(Gb + ((long)s2 << 6) + fo);
            uint4 v3 = *(const uint4*)(Gb + ((long)s3 << 6) + fo);
            uint4 v4 = *(const uint4*)(Gb + ((long)s4 << 6) + fo);
            uint4 v5 = *(const uint4*)(Gb + ((long)s5 << 6) + fo);
            uint4 v6 = *(const uint4*)(Gb + ((long)s6 << 6) + fo);
            uint4 v7 = *(const uint4*)(Gb + ((long)s7 << 6) + fo);
            ACC8(v0); ACC8(v1); ACC8(v2); ACC8(v3);
            ACC8(v4); ACC8(v5); ACC8(v6); ACC8(v7);
        }
        for (; i + 1 < end; i += 2) {
            int s0 = csr[i], s1 = csr[i + 1];
            uint4 v0 = *(const uint4*)(Gb + ((long)s0 << 6) + fo);
            uint4 v1 = *(const uint4*)(Gb + ((long)s1 << 6) + fo);
            ACC8(v0); ACC8(v1);
        }
        if (i < end) {
            int s0 = csr[i];
            uint4 v0 = *(const uint4*)(Gb + ((long)s0 << 6) + fo);
            ACC8(v0);
        }
        uint4 o;
        o.x = bf1(acc[0]) | (bf1(acc[1]) << 16);
        o.y = bf1(acc[2]) | (bf1(acc[3]) << 16);
        o.z = bf1(acc[4]) | (bf1(acc[5]) << 16);
        o.w = bf1(acc[6]) | (bf1(acc[7]) << 16);
        *(uint4*)&z_s[nl * 72 + fo] = o;
    }
    __syncthreads();

    // ---- MFMA: 8 waves = 4 node-groups x 2 col-halves ----
    const int lane = tid & 63;
    const int wid = tid >> 6;
    const int rbase = (wid >> 1) * 16;
    const int cbase = (wid & 1) * 32;
    const int r16 = lane & 15;
    const int kg = lane >> 4;
    const int c0 = cbase + r16;
    const int c1 = cbase + 16 + r16;

    // layer 1
    frag a0 = *(const frag*)&z_s[(rbase + r16) * 72 + kg * 8];
    frag a1 = *(const frag*)&z_s[(rbase + r16) * 72 + 32 + kg * 8];
    frag b00 = *(const frag*)&w_s[0][c0 * 72 + kg * 8];
    frag b01 = *(const frag*)&w_s[0][c0 * 72 + 32 + kg * 8];
    frag b10 = *(const frag*)&w_s[0][c1 * 72 + kg * 8];
    frag b11 = *(const frag*)&w_s[0][c1 * 72 + 32 + kg * 8];
    f32x4 acc0, acc1;
    #pragma unroll
    for (int r = 0; r < 4; ++r) { acc0[r] = sb[0][c0]; acc1[r] = sb[0][c1]; }
    acc0 = __builtin_amdgcn_mfma_f32_16x16x32_bf16(a0, b00, acc0, 0, 0, 0);
    acc0 = __builtin_amdgcn_mfma_f32_16x16x32_bf16(a1, b01, acc0, 0, 0, 0);
    acc1 = __builtin_amdgcn_mfma_f32_16x16x32_bf16(a0, b10, acc1, 0, 0, 0);
    acc1 = __builtin_amdgcn_mfma_f32_16x16x32_bf16(a1, b11, acc1, 0, 0, 0);
    __syncthreads();

    // y = relu -> bf16 back into z_s
    #pragma unroll
    for (int r = 0; r < 4; ++r) {
        int row = rbase + kg * 4 + r;
        float y0 = acc0[r] > 0.f ? acc0[r] : 0.f;
        float y1 = acc1[r] > 0.f ? acc1[r] : 0.f;
        z_s[row * 72 + c0] = (ushort)bf1(y0);
        z_s[row * 72 + c1] = (ushort)bf1(y1);
    }
    __syncthreads();

    // layer 2
    a0 = *(const frag*)&z_s[(rbase + r16) * 72 + kg * 8];
    a1 = *(const frag*)&z_s[(rbase + r16) * 72 + 32 + kg * 8];
    b00 = *(const frag*)&w_s[1][c0 * 72 + kg * 8];
    b01 = *(const frag*)&w_s[1][c0 * 72 + 32 + kg * 8];
    b10 = *(const frag*)&w_s[1][c1 * 72 + kg * 8];
    b11 = *(const frag*)&w_s[1][c1 * 72 + 32 + kg * 8];
    #pragma unroll
    for (int r = 0; r < 4; ++r) { acc0[r] = sb[1][c0]; acc1[r] = sb[1][c1]; }
    acc0 = __builtin_amdgcn_mfma_f32_16x16x32_bf16(a0, b00, acc0, 0, 0, 0);
    acc0 = __builtin_amdgcn_mfma_f32_16x16x32_bf16(a1, b01, acc0, 0, 0, 0);
    acc1 = __builtin_amdgcn_mfma_f32_16x16x32_bf16(a0, b10, acc1, 0, 0, 0);
    acc1 = __builtin_amdgcn_mfma_f32_16x16x32_bf16(a1, b11, acc1, 0, 0, 0);

    if (MODE == 0) {
        #pragma unroll
        for (int r = 0; r < 4; ++r) {
            long node = nbase + rbase + kg * 4 + r;
            float v0 = acc0[r] > 0.f ? acc0[r] : 0.f;
            float v1 = acc1[r] > 0.f ? acc1[r] : 0.f;
            OutB[node * D + c0] = (ushort)bf1(v0);
            OutB[node * D + c1] = (ushort)bf1(v1);
        }
    } else {
        // conv2 epilogue: fused graph pooling (sum + max)
        __syncthreads();
        float* pbuf = (float*)&w_s[0][0];      // [64][66] fp32
        #pragma unroll
        for (int r = 0; r < 4; ++r) {
            int row = rbase + kg * 4 + r;
            pbuf[row * 66 + c0] = acc0[r];
            pbuf[row * 66 + c1] = acc1[r];
        }
        if (tid < 64) sgid[tid] = batch[nbase + tid];
        __syncthreads();
        const int g0 = sgid[0], g1 = sgid[63];
        float* rsum = (float*)&z_s[0];         // [8][64]
        float* rmax = rsum + 512;
        const int col = tid & 63;
        const int ch = tid >> 6;
        for (int g = g0; ; ++g) {
            float s = 0.f, m = -INFINITY;
            #pragma unroll
            for (int r = 0; r < 8; ++r) {
                int row = ch * 8 + r;
                if (sgid[row] == g) {
                    float v = pbuf[row * 66 + col];
                    s += v;
                    m = m > v ? m : v;
                }
            }
            rsum[ch * 64 + col] = s;
            rmax[ch * 64 + col] = m;
            __syncthreads();
            if (tid < 64) {
                float S = 0.f, M = -INFINITY;
                #pragma unroll
                for (int c = 0; c < 8; ++c) {
                    S += rsum[c * 64 + tid];
                    float mm = rmax[c * 64 + tid];
                    M = M > mm ? M : mm;
                }
                atomicAdd(&psum[g * 64 + tid], S);
                atomicMaxFloat(&pmax[g * 64 + tid], M);
            }
            if (g == g1) break;
            __syncthreads();
        }
    }
}

// ================= MLP head =================
__device__ inline float silu(float x) { return x / (1.f + expf(-x)); }

__global__ __launch_bounds__(128) void k_head(
    const float* __restrict__ psum, const float* __restrict__ pmax,
    const float* __restrict__ w0, const float* __restrict__ b0,
    const float* __restrict__ w1, const float* __restrict__ b1,
    const float* __restrict__ w2, const float* __restrict__ b2,
    const float* __restrict__ w3, const float* __restrict__ b3,
    const float* __restrict__ w4, const float* __restrict__ b4,
    float* __restrict__ out)
{
    __shared__ float bufA[128];
    __shared__ float bufB[128];
    int g = blockIdx.x, t = threadIdx.x;
    bufA[t] = (t < 64) ? psum[g * 64 + t] : pmax[g * 64 + (t - 64)];
    __syncthreads();
    {
        float a = b0[t];
        for (int k = 0; k < 128; ++k) a += bufA[k] * w0[k * 128 + t];
        bufB[t] = silu(a);
    }
    __syncthreads();
    if (t < 64) {
        float a = b1[t];
        for (int k = 0; k < 128; ++k) a += bufB[k] * w1[k * 64 + t];
        bufA[t] = silu(a);
    }
    __syncthreads();
    if (t < 32) {
        float a = b2[t];
        for (int k = 0; k < 64; ++k) a += bufA[k] * w2[k * 32 + t];
        bufB[t] = silu(a);
    }
    __syncthreads();
    if (t < 16) {
        float a = b3[t];
        for (int k = 0; k < 32; ++k) a += bufB[k] * w3[k * 16 + t];
        bufA[t] = silu(a);
    }
    __syncthreads();
    if (t == 0) {
        float a = b4[0];
        for (int k = 0; k < 16; ++k) a += bufA[k] * w4[k];
        out[g] = a;
    }
}

extern "C" void kernel_launch(void* const* d_in, const int* in_sizes, int n_in,
                              void* d_out, int out_size, void* d_ws, size_t ws_size,
                              hipStream_t stream) {
    const float* x     = (const float*)d_in[0];
    const int*   ei    = (const int*)d_in[1];
    const int*   batch = (const int*)d_in[2];
    const float* c1w1 = (const float*)d_in[3];
    const float* c1b1 = (const float*)d_in[4];
    const float* c1w2 = (const float*)d_in[5];
    const float* c1b2 = (const float*)d_in[6];
    const float* c2w1 = (const float*)d_in[7];
    const float* c2b1 = (const float*)d_in[8];
    const float* c2w2 = (const float*)d_in[9];
    const float* c2b2 = (const float*)d_in[10];
    const float* hw0 = (const float*)d_in[11];
    const float* hb0 = (const float*)d_in[12];
    const float* hw1 = (const float*)d_in[13];
    const float* hb1 = (const float*)d_in[14];
    const float* hw2 = (const float*)d_in[15];
    const float* hb2 = (const float*)d_in[16];
    const float* hw3 = (const float*)d_in[17];
    const float* hb3 = (const float*)d_in[18];
    const float* hw4 = (const float*)d_in[19];
    const float* hb4 = (const float*)d_in[20];

    const size_t NF = (size_t)N_NODES * D;
    ushort* xb   = (ushort*)d_ws;                       // 25.6 MB
    ushort* hb   = xb + NF;                             // 25.6 MB
    float*  psum = (float*)(hb + NF);                   // 32 KB
    float*  pmax = psum + NGRAPH * D;                   // 32 KB
    int* gcur    = (int*)(pmax + NGRAPH * D);           // 256
    int2* rows   = (int2*)(gcur + 256);                 // 200000 int2 (1.6 MB)
    int* csr     = (int*)(rows + N_NODES);              // BKT*BCAP (6.4 MB)
    uint* recs   = (uint*)(csr + BKT * BCAP);           // BKT*BCAP (6.4 MB)
    float* out   = (float*)d_out;

    const int* srcs = ei;
    const int* dsts = ei + N_EDGES;

    const int convBlocks = N_NODES / 64;                // 3125

    // 1. zero bucket counters
    hipMemsetAsync(gcur, 0, 256 * sizeof(int), stream);

    // 2. partition edges + bf16 cast of x + pool init
    k_part_cast<<<PARTB + CASTB + INITB, 256, 0, stream>>>(
        srcs, dsts, gcur, recs, x, xb, psum, pmax);

    // 3. bucket-local CSR build
    k_fill2<<<BKT, 512, 0, stream>>>(recs, gcur, csr, rows);

    // 4. conv1: self+gather from xb -> hb (bf16 only)
    k_conv<0><<<convBlocks, 512, 0, stream>>>(
        xb, rows, csr, c1w1, c1b1, c1w2, c1b2,
        hb, (const int*)nullptr, (float*)nullptr, (float*)nullptr);

    // 5. conv2: self+gather from hb -> fused pooling into psum/pmax
    k_conv<1><<<convBlocks, 512, 0, stream>>>(
        hb, rows, csr, c2w1, c2b1, c2w2, c2b2,
        (ushort*)nullptr, batch, psum, pmax);

    // 6. head
    k_head<<<NGRAPH, 128, 0, stream>>>(psum, pmax,
                                       hw0, hb0, hw1, hb1, hw2, hb2, hw3, hb3, hw4, hb4,
                                       out);
}